// Round 4
// baseline (2363.070 us; speedup 1.0000x reference)
//
#include <hip/hip_runtime.h>
#include <hip/hip_bf16.h>
#include <math.h>

#define B_ 4
#define T_ 2048
#define E_ 768
#define H_ 3
#define D_ 256

// ---------------------------------------------------------------------------
// Tiled FP32 GEMM: C[M,N] = A[M,K] * B[K,N] (+bias), row-major.
// Block 256 threads, tile 128x128, K-step 16, 8x8 micro-tile per thread.
// Compute:LDS cycle ratio per e-step: 64 FMA (128 cyc wave64) vs 4 ds_read_b128
// (~48 cyc) -> compute-bound inner loop (the 64x64/4x4 version was ~1:1).
// Batched over blockIdx.z: A += (z/Hdiv)*sA, B += (z%Hdiv)*sB, C += z*sC.
// As staged transposed [16][132]; Bs [16][132] (132 = mult-of-4 pad:
// float4-aligned rows, breaks power-of-2 bank stride).
// ---------------------------------------------------------------------------
#define BM 128
#define BN 128
#define BK 16

__global__ __launch_bounds__(256)
void sgemm128(const float* __restrict__ A, const float* __restrict__ Bm,
              float* __restrict__ C, const float* __restrict__ bias,
              int Kdim, int Hdiv, int lda, int ldb, int ldc,
              long sA, long sB, long sC)
{
    __shared__ float As[BK][BM + 4];   // transposed: As[k][m]
    __shared__ float Bs[BK][BN + 4];   // Bs[k][n]

    const int z = blockIdx.z;
    A  += (long)(z / Hdiv) * sA;
    Bm += (long)(z % Hdiv) * sB;
    C  += (long)z * sC;

    const int m0 = blockIdx.y * BM;
    const int n0 = blockIdx.x * BN;
    const int tid = threadIdx.x;
    const int ty = tid >> 4;      // 0..15 -> rows ty*8..ty*8+7
    const int tx = tid & 15;      // 0..15 -> cols tx*8..tx*8+7

    float acc[8][8];
    #pragma unroll
    for (int i = 0; i < 8; ++i)
        #pragma unroll
        for (int jj = 0; jj < 8; ++jj) acc[i][jj] = 0.f;

    for (int k0 = 0; k0 < Kdim; k0 += BK) {
        // ---- stage A tile (128 rows x 16 cols), transposed into As ----
        #pragma unroll
        for (int it = 0; it < 2; ++it) {
            const int L  = tid + it * 256;      // float4 index in [0,512)
            const int rm = L >> 2;              // A-tile row 0..127
            const int rk = (L & 3) << 2;        // A-tile col 0,4,8,12
            float4 a4 = *(const float4*)(A + (long)(m0 + rm) * lda + k0 + rk);
            As[rk + 0][rm] = a4.x;
            As[rk + 1][rm] = a4.y;
            As[rk + 2][rm] = a4.z;
            As[rk + 3][rm] = a4.w;
        }
        // ---- stage B tile (16 rows x 128 cols) ----
        #pragma unroll
        for (int it = 0; it < 2; ++it) {
            const int L  = tid + it * 256;      // float4 index in [0,512)
            const int rk = L >> 5;              // B-tile row 0..15
            const int rn = (L & 31) << 2;       // B-tile col 0..124
            float4 b4 = *(const float4*)(Bm + (long)(k0 + rk) * ldb + n0 + rn);
            *(float4*)&Bs[rk][rn] = b4;
        }
        __syncthreads();

        #pragma unroll
        for (int e = 0; e < BK; ++e) {
            float a_[8], b_[8];
            *(float4*)&a_[0] = *(const float4*)&As[e][ty * 8];
            *(float4*)&a_[4] = *(const float4*)&As[e][ty * 8 + 4];
            *(float4*)&b_[0] = *(const float4*)&Bs[e][tx * 8];
            *(float4*)&b_[4] = *(const float4*)&Bs[e][tx * 8 + 4];
            #pragma unroll
            for (int i = 0; i < 8; ++i)
                #pragma unroll
                for (int jj = 0; jj < 8; ++jj)
                    acc[i][jj] = fmaf(a_[i], b_[jj], acc[i][jj]);
        }
        __syncthreads();
    }

    float bb[8];
    #pragma unroll
    for (int jj = 0; jj < 8; ++jj) bb[jj] = 0.f;
    if (bias) {
        *(float4*)&bb[0] = *(const float4*)(bias + n0 + tx * 8);
        *(float4*)&bb[4] = *(const float4*)(bias + n0 + tx * 8 + 4);
    }
    #pragma unroll
    for (int i = 0; i < 8; ++i) {
        float* crow = C + (long)(m0 + ty * 8 + i) * ldc + n0 + tx * 8;
        float4 o0, o1;
        o0.x = acc[i][0] + bb[0]; o0.y = acc[i][1] + bb[1];
        o0.z = acc[i][2] + bb[2]; o0.w = acc[i][3] + bb[3];
        o1.x = acc[i][4] + bb[4]; o1.y = acc[i][5] + bb[5];
        o1.z = acc[i][6] + bb[6]; o1.w = acc[i][7] + bb[7];
        *(float4*)(crow + 0) = o0;
        *(float4*)(crow + 4) = o1;
    }
}

// ---------------------------------------------------------------------------
// Causal flash attention, fp32.  Q,K,V: [B*H, T, D] row-major.
// Grid (T/32, B*H), block 256 (4 waves).
// Thread (r = tid/8, j = tid&7) owns row q0+r, columns j*32 .. j*32+31.
// Q and O accumulator in registers; scores s[32] in registers via 8-lane
// shfl_xor partial-dot reduction (lanes sharing a row are consecutive).
// K/V tiles in LDS with skew p = c + (c>>5)*4, stride 288:
//   read addr = k*288 + j*36 + i  -> contiguous in i (float4-able),
//   bank base = (4j + 4*i4) % 32  -> 8 distinct bank-quads, conflict-free.
// Output written directly in head-concat layout Z2[B, T, H*D].
// ---------------------------------------------------------------------------
__global__ __launch_bounds__(256)
void flash32(const float* __restrict__ Qp, const float* __restrict__ Kp,
             const float* __restrict__ Vp, float* __restrict__ Z2, float scale)
{
    __shared__ float Ks[32 * 288];
    __shared__ float Vs[32 * 288];

    const int bh = blockIdx.y;
    const int b  = bh / H_;
    const int h  = bh % H_;
    const int q0 = blockIdx.x * 32;
    const int tid = threadIdx.x;
    const int r = tid >> 3;   // 0..31 row within q-tile
    const int j = tid & 7;    // 0..7  column group

    const float* Qrow = Qp + ((long)bh * T_ + q0 + r) * D_ + j * 32;
    float q[32], o[32];
    #pragma unroll
    for (int i4 = 0; i4 < 8; ++i4) {
        float4 t4 = *(const float4*)(Qrow + i4 * 4);
        q[i4 * 4 + 0] = t4.x; q[i4 * 4 + 1] = t4.y;
        q[i4 * 4 + 2] = t4.z; q[i4 * 4 + 3] = t4.w;
    }
    #pragma unroll
    for (int i = 0; i < 32; ++i) o[i] = 0.f;
    float m = -INFINITY, l = 0.f;

    const float4* Kbase = (const float4*)(Kp + (long)bh * T_ * D_);
    const float4* Vbase = (const float4*)(Vp + (long)bh * T_ * D_);

    for (int k0 = 0; k0 <= q0; k0 += 32) {
        // ---- stage K,V tile (32x256 each), skewed ----
        const float4* ksrc = Kbase + (long)k0 * (D_ / 4);
        const float4* vsrc = Vbase + (long)k0 * (D_ / 4);
        #pragma unroll
        for (int it = 0; it < 8; ++it) {
            int L  = tid + it * 256;        // float4 index within 32x256 tile
            int kk = L >> 6;                // row
            int c  = (L & 63) << 2;         // float col
            int p  = c + ((c >> 5) << 2);   // skew
            *(float4*)&Ks[kk * 288 + p] = ksrc[L];
            *(float4*)&Vs[kk * 288 + p] = vsrc[L];
        }
        __syncthreads();

        // ---- scores: s_[k] = dot(Q[r,:], K[k,:]) * scale ----
        float s_[32];
        const bool diag = (k0 == q0);
        #pragma unroll
        for (int k = 0; k < 32; ++k) {
            const float* kr = &Ks[k * 288 + j * 36];
            float acc = 0.f;
            #pragma unroll
            for (int i4 = 0; i4 < 8; ++i4) {
                float4 kv = *(const float4*)(kr + i4 * 4);
                acc = fmaf(q[i4 * 4 + 0], kv.x, acc);
                acc = fmaf(q[i4 * 4 + 1], kv.y, acc);
                acc = fmaf(q[i4 * 4 + 2], kv.z, acc);
                acc = fmaf(q[i4 * 4 + 3], kv.w, acc);
            }
            acc += __shfl_xor(acc, 1);
            acc += __shfl_xor(acc, 2);
            acc += __shfl_xor(acc, 4);
            acc *= scale;
            if (diag && (k > r)) acc = -INFINITY;  // causal: k0+k > q0+r
            s_[k] = acc;
        }

        // ---- online softmax (replicated across the 8 lanes of a row) ----
        float tmax = s_[0];
        #pragma unroll
        for (int k = 1; k < 32; ++k) tmax = fmaxf(tmax, s_[k]);
        float mnew  = fmaxf(m, tmax);
        float alpha = __expf(m - mnew);   // first tile: exp(-inf)=0
        float psum  = 0.f;
        #pragma unroll
        for (int k = 0; k < 32; ++k) {
            float p = __expf(s_[k] - mnew);
            s_[k] = p;
            psum += p;
        }
        l = l * alpha + psum;
        m = mnew;
        #pragma unroll
        for (int i = 0; i < 32; ++i) o[i] *= alpha;

        // ---- O += P * V ----
        #pragma unroll
        for (int k = 0; k < 32; ++k) {
            const float p = s_[k];
            const float* vr = &Vs[k * 288 + j * 36];
            #pragma unroll
            for (int i4 = 0; i4 < 8; ++i4) {
                float4 vv = *(const float4*)(vr + i4 * 4);
                o[i4 * 4 + 0] = fmaf(p, vv.x, o[i4 * 4 + 0]);
                o[i4 * 4 + 1] = fmaf(p, vv.y, o[i4 * 4 + 1]);
                o[i4 * 4 + 2] = fmaf(p, vv.z, o[i4 * 4 + 2]);
                o[i4 * 4 + 3] = fmaf(p, vv.w, o[i4 * 4 + 3]);
            }
        }
        __syncthreads();
    }

    const float inv_l = 1.0f / l;
    float* dst = Z2 + ((long)b * T_ + q0 + r) * E_ + h * D_ + j * 32;
    #pragma unroll
    for (int i4 = 0; i4 < 8; ++i4) {
        float4 o4;
        o4.x = o[i4 * 4 + 0] * inv_l;
        o4.y = o[i4 * 4 + 1] * inv_l;
        o4.z = o[i4 * 4 + 2] * inv_l;
        o4.w = o[i4 * 4 + 3] * inv_l;
        *(float4*)(dst + i4 * 4) = o4;
    }
}

// ---------------------------------------------------------------------------
// d_in order: keys, values, queries, Wk, Wq, Wv, Wo, bo  (all fp32)
// Workspace: Kp | Vp | Qp  (each B*H*T*D) | Z2 (B*T*E)  = 100.7 MB total.
// ---------------------------------------------------------------------------
extern "C" void kernel_launch(void* const* d_in, const int* in_sizes, int n_in,
                              void* d_out, int out_size, void* d_ws, size_t ws_size,
                              hipStream_t stream)
{
    const float* Xk = (const float*)d_in[0];
    const float* Xv = (const float*)d_in[1];
    const float* Xq = (const float*)d_in[2];
    const float* Wk = (const float*)d_in[3];
    const float* Wq = (const float*)d_in[4];
    const float* Wv = (const float*)d_in[5];
    const float* Wo = (const float*)d_in[6];
    const float* bo = (const float*)d_in[7];
    float* out = (float*)d_out;

    const size_t phd = (size_t)B_ * H_ * T_ * D_;  // 6,291,456
    float* Kp = (float*)d_ws;
    float* Vp = Kp + phd;
    float* Qp = Vp + phd;
    float* Z2 = Qp + phd;                          // B*T*E, same count

    dim3 blk(256);

    // Projections: per (b,h): [T,E] x [E,D] -> [T,D], laid out [B,H,T,D]
    dim3 gproj(D_ / BN, T_ / BM, B_ * H_);         // (2, 16, 12)
    const long sA = (long)T_ * E_, sB = (long)E_ * D_, sC = (long)T_ * D_;
    sgemm128<<<gproj, blk, 0, stream>>>(Xk, Wk, Kp, nullptr, E_, H_, E_, D_, D_, sA, sB, sC);
    sgemm128<<<gproj, blk, 0, stream>>>(Xv, Wv, Vp, nullptr, E_, H_, E_, D_, D_, sA, sB, sC);
    sgemm128<<<gproj, blk, 0, stream>>>(Xq, Wq, Qp, nullptr, E_, H_, E_, D_, D_, sA, sB, sC);

    // Causal flash attention -> Z2 in [B, T, H*D] layout
    dim3 gf(T_ / 32, B_ * H_);
    flash32<<<gf, blk, 0, stream>>>(Qp, Kp, Vp, Z2, 0.022097086912079608f /* 1/sqrt(2048) */);

    // Output projection: [B*T, E] x [E, E] + bo
    dim3 gout(E_ / BN, (B_ * T_) / BM, 1);         // (6, 64, 1)
    sgemm128<<<gout, blk, 0, stream>>>(Z2, Wo, out, bo, E_, 1, E_, E_, E_, 0L, 0L, 0L);
}

// Round 5
// 1627.647 us; speedup vs baseline: 1.4518x; 1.4518x over previous
//
#include <hip/hip_runtime.h>
#include <hip/hip_bf16.h>
#include <math.h>

#define B_ 4
#define T_ 2048
#define E_ 768
#define H_ 3
#define D_ 256

typedef __attribute__((ext_vector_type(8))) short short8;
typedef __attribute__((ext_vector_type(8))) unsigned short ushort8;
typedef __attribute__((ext_vector_type(4))) float f32x4;

static __device__ inline unsigned short f2bf(float x) {
    __hip_bfloat16 h = __float2bfloat16(x);
    return *reinterpret_cast<unsigned short*>(&h);
}

// ---------------------------------------------------------------------------
// Transpose + fp32->bf16 cast: in [z][R][C] fp32  ->  out [z][C][R] bf16.
// Makes weights [N][K] so GEMM B-tiles are k-contiguous (same LDS layout as A).
// ---------------------------------------------------------------------------
__global__ __launch_bounds__(256)
void transpose_cast(const float* __restrict__ in, unsigned short* __restrict__ out,
                    int R, int Ccols)
{
    __shared__ float tile[32][33];
    const long zoff = (long)blockIdx.z * R * Ccols;
    const int c0 = blockIdx.x * 32;
    const int r0 = blockIdx.y * 32;
    const int t  = threadIdx.x;
    const int cc = t & 31, rr = t >> 5;           // rr 0..7
    #pragma unroll
    for (int i = 0; i < 4; ++i)
        tile[rr + i * 8][cc] = in[zoff + (long)(r0 + rr + i * 8) * Ccols + c0 + cc];
    __syncthreads();
    const int rr2 = t & 31, cc2 = t >> 5;         // write: r inner -> coalesced
    #pragma unroll
    for (int i = 0; i < 4; ++i)
        out[zoff + (long)(c0 + cc2 + i * 8) * R + r0 + rr2] = f2bf(tile[rr2][cc2 + i * 8]);
}

// ---------------------------------------------------------------------------
// bf16 MFMA GEMM: C[M,N] fp32 = A[M,K] * B^T  (Bt given as [N][K] bf16).
// Block 256 (4 waves, 2x2 wave grid of 64x64), tile 128x128, BK=32.
// LDS: As[128][32] bf16, Bs[128][32] bf16 (both k-contiguous; 64B row stride
// naturally interleaves bank-quads -> conflict-free b128 frag reads).
// A is fp32 (CONVA: fused cast during staging) or bf16 (CONVA=false).
// mfma_f32_16x16x32_bf16: A row=lane&15,k=(lane>>4)*8+e; B col=lane&15,same k;
// C/D col=lane&15, row=(lane>>4)*4+reg  [guide §3, m89/m91 verified].
// ---------------------------------------------------------------------------
template<bool CONVA>
__global__ __launch_bounds__(256)
void gemm_mfma(const void* __restrict__ Av, const unsigned short* __restrict__ Bt,
               float* __restrict__ C, const float* __restrict__ bias,
               int K, int Hdiv, int lda, int ldc, long sA, long sB, long sC)
{
    __shared__ unsigned short As[128 * 32];
    __shared__ unsigned short Bs[128 * 32];

    const int z = blockIdx.z;
    const float*          Af = (const float*)Av          + (long)(z / Hdiv) * sA;
    const unsigned short* Ah = (const unsigned short*)Av + (long)(z / Hdiv) * sA;
    const unsigned short* Bz = Bt + (long)(z % Hdiv) * sB;
    float* Cz = C + (long)z * sC;

    const int m0 = blockIdx.y * 128, n0 = blockIdx.x * 128;
    const int tid  = threadIdx.x;
    const int lane = tid & 63, wid = tid >> 6;
    const int wm = wid >> 1, wn = wid & 1;        // wave covers rows wm*64, cols wn*64
    const int fr = lane & 15, fg = lane >> 4;     // frag row/col, k-group

    f32x4 acc[4][4];
    #pragma unroll
    for (int mt = 0; mt < 4; ++mt)
        #pragma unroll
        for (int nt = 0; nt < 4; ++nt) acc[mt][nt] = (f32x4)(0.f);

    for (int k0 = 0; k0 < K; k0 += 32) {
        // stage A-tile [128 m][32 k] and B-tile [128 n][32 k]; 2 granules each/thread
        #pragma unroll
        for (int i = 0; i < 2; ++i) {
            const int G = tid + i * 256;          // granule = 8 bf16 = 16B
            const int row = G >> 2, g = G & 3;
            ushort8 pa;
            if (CONVA) {
                const float* s = Af + (long)(m0 + row) * lda + k0 + g * 8;
                float4 f0 = *(const float4*)s, f1 = *(const float4*)(s + 4);
                pa[0] = f2bf(f0.x); pa[1] = f2bf(f0.y); pa[2] = f2bf(f0.z); pa[3] = f2bf(f0.w);
                pa[4] = f2bf(f1.x); pa[5] = f2bf(f1.y); pa[6] = f2bf(f1.z); pa[7] = f2bf(f1.w);
            } else {
                pa = *(const ushort8*)(Ah + (long)(m0 + row) * lda + k0 + g * 8);
            }
            *(ushort8*)&As[row * 32 + g * 8] = pa;
            *(ushort8*)&Bs[row * 32 + g * 8] =
                *(const ushort8*)(Bz + (long)(n0 + row) * K + k0 + g * 8);
        }
        __syncthreads();

        short8 a[4], b[4];
        #pragma unroll
        for (int mt = 0; mt < 4; ++mt)
            a[mt] = *(const short8*)&As[(wm * 64 + mt * 16 + fr) * 32 + fg * 8];
        #pragma unroll
        for (int nt = 0; nt < 4; ++nt)
            b[nt] = *(const short8*)&Bs[(wn * 64 + nt * 16 + fr) * 32 + fg * 8];
        #pragma unroll
        for (int mt = 0; mt < 4; ++mt)
            #pragma unroll
            for (int nt = 0; nt < 4; ++nt)
                acc[mt][nt] = __builtin_amdgcn_mfma_f32_16x16x32_bf16(
                                  a[mt], b[nt], acc[mt][nt], 0, 0, 0);
        __syncthreads();
    }

    // epilogue: lane -> col = ..+fr, rows = ..+fg*4+reg
    #pragma unroll
    for (int nt = 0; nt < 4; ++nt) {
        const int col = n0 + wn * 64 + nt * 16 + fr;
        const float badd = bias ? bias[col] : 0.f;
        #pragma unroll
        for (int mt = 0; mt < 4; ++mt) {
            const int row = m0 + wm * 64 + mt * 16 + fg * 4;
            #pragma unroll
            for (int reg = 0; reg < 4; ++reg)
                Cz[(long)(row + reg) * ldc + col] = acc[mt][nt][reg] + badd;
        }
    }
}

// ---------------------------------------------------------------------------
// Causal flash attention, fp32 math, bf16 output.  Q,K,V: [B*H, T, D] fp32.
// Grid (T/32, B*H) with REVERSED q-tile order (heavy blocks dispatch first).
// Thread (r=tid/8, j=tid&7) owns row q0+r, cols j*32..j*32+31.
// Score dot uses 4 parallel partial accumulators (breaks the 32-deep
// dependent FMA chain that made the kernel latency-bound at 17% VALUBusy).
// Output written bf16 directly into Z2h[B, T, H*D] (feeds final MFMA GEMM).
// ---------------------------------------------------------------------------
__global__ __launch_bounds__(256)
void flash32(const float* __restrict__ Qp, const float* __restrict__ Kp,
             const float* __restrict__ Vp, unsigned short* __restrict__ Z2h,
             float scale)
{
    __shared__ float Ks[32 * 288];
    __shared__ float Vs[32 * 288];

    const int bh = blockIdx.y;
    const int b  = bh / H_;
    const int h  = bh % H_;
    const int q0 = (gridDim.x - 1 - blockIdx.x) * 32;   // reversed: longest first
    const int tid = threadIdx.x;
    const int r = tid >> 3;
    const int j = tid & 7;

    const float* Qrow = Qp + ((long)bh * T_ + q0 + r) * D_ + j * 32;
    float q[32], o[32];
    #pragma unroll
    for (int i4 = 0; i4 < 8; ++i4) {
        float4 t4 = *(const float4*)(Qrow + i4 * 4);
        q[i4 * 4 + 0] = t4.x; q[i4 * 4 + 1] = t4.y;
        q[i4 * 4 + 2] = t4.z; q[i4 * 4 + 3] = t4.w;
    }
    #pragma unroll
    for (int i = 0; i < 32; ++i) o[i] = 0.f;
    float m = -INFINITY, l = 0.f;

    const float4* Kbase = (const float4*)(Kp + (long)bh * T_ * D_);
    const float4* Vbase = (const float4*)(Vp + (long)bh * T_ * D_);

    for (int k0 = 0; k0 <= q0; k0 += 32) {
        const float4* ksrc = Kbase + (long)k0 * (D_ / 4);
        const float4* vsrc = Vbase + (long)k0 * (D_ / 4);
        #pragma unroll
        for (int it = 0; it < 8; ++it) {
            int L  = tid + it * 256;
            int kk = L >> 6;
            int c  = (L & 63) << 2;
            int p  = c + ((c >> 5) << 2);   // skew: conflict-free reads at j*36
            *(float4*)&Ks[kk * 288 + p] = ksrc[L];
            *(float4*)&Vs[kk * 288 + p] = vsrc[L];
        }
        __syncthreads();

        float s_[32];
        const bool diag = (k0 == q0);
        #pragma unroll
        for (int k = 0; k < 32; ++k) {
            const float* kr = &Ks[k * 288 + j * 36];
            float ac0 = 0.f, ac1 = 0.f, ac2 = 0.f, ac3 = 0.f;  // 4-way ILP
            #pragma unroll
            for (int i4 = 0; i4 < 8; i4 += 4) {
                float4 k0v = *(const float4*)(kr + (i4 + 0) * 4);
                float4 k1v = *(const float4*)(kr + (i4 + 1) * 4);
                float4 k2v = *(const float4*)(kr + (i4 + 2) * 4);
                float4 k3v = *(const float4*)(kr + (i4 + 3) * 4);
                ac0 = fmaf(q[(i4+0)*4+0], k0v.x, ac0); ac0 = fmaf(q[(i4+0)*4+1], k0v.y, ac0);
                ac0 = fmaf(q[(i4+0)*4+2], k0v.z, ac0); ac0 = fmaf(q[(i4+0)*4+3], k0v.w, ac0);
                ac1 = fmaf(q[(i4+1)*4+0], k1v.x, ac1); ac1 = fmaf(q[(i4+1)*4+1], k1v.y, ac1);
                ac1 = fmaf(q[(i4+1)*4+2], k1v.z, ac1); ac1 = fmaf(q[(i4+1)*4+3], k1v.w, ac1);
                ac2 = fmaf(q[(i4+2)*4+0], k2v.x, ac2); ac2 = fmaf(q[(i4+2)*4+1], k2v.y, ac2);
                ac2 = fmaf(q[(i4+2)*4+2], k2v.z, ac2); ac2 = fmaf(q[(i4+2)*4+3], k2v.w, ac2);
                ac3 = fmaf(q[(i4+3)*4+0], k3v.x, ac3); ac3 = fmaf(q[(i4+3)*4+1], k3v.y, ac3);
                ac3 = fmaf(q[(i4+3)*4+2], k3v.z, ac3); ac3 = fmaf(q[(i4+3)*4+3], k3v.w, ac3);
            }
            float acc = (ac0 + ac1) + (ac2 + ac3);
            acc += __shfl_xor(acc, 1);
            acc += __shfl_xor(acc, 2);
            acc += __shfl_xor(acc, 4);
            acc *= scale;
            if (diag && (k > r)) acc = -INFINITY;
            s_[k] = acc;
        }

        float tmax = s_[0];
        #pragma unroll
        for (int k = 1; k < 32; ++k) tmax = fmaxf(tmax, s_[k]);
        float mnew  = fmaxf(m, tmax);
        float alpha = __expf(m - mnew);
        float psum  = 0.f;
        #pragma unroll
        for (int k = 0; k < 32; ++k) {
            float p = __expf(s_[k] - mnew);
            s_[k] = p;
            psum += p;
        }
        l = l * alpha + psum;
        m = mnew;
        #pragma unroll
        for (int i = 0; i < 32; ++i) o[i] *= alpha;

        #pragma unroll
        for (int k = 0; k < 32; ++k) {
            const float p = s_[k];
            const float* vr = &Vs[k * 288 + j * 36];
            #pragma unroll
            for (int i4 = 0; i4 < 8; ++i4) {
                float4 vv = *(const float4*)(vr + i4 * 4);
                o[i4 * 4 + 0] = fmaf(p, vv.x, o[i4 * 4 + 0]);
                o[i4 * 4 + 1] = fmaf(p, vv.y, o[i4 * 4 + 1]);
                o[i4 * 4 + 2] = fmaf(p, vv.z, o[i4 * 4 + 2]);
                o[i4 * 4 + 3] = fmaf(p, vv.w, o[i4 * 4 + 3]);
            }
        }
        __syncthreads();
    }

    const float inv_l = 1.0f / l;
    unsigned short* dst = Z2h + ((long)b * T_ + q0 + r) * E_ + h * D_ + j * 32;
    #pragma unroll
    for (int g = 0; g < 4; ++g) {
        ushort8 pk;
        #pragma unroll
        for (int e = 0; e < 8; ++e) pk[e] = f2bf(o[g * 8 + e] * inv_l);
        *(ushort8*)(dst + g * 8) = pk;
    }
}

// ---------------------------------------------------------------------------
// d_in: keys, values, queries, Wk, Wq, Wv, Wo, bo (all fp32)
// ws: Kp|Vp|Qp fp32 (75.5MB) | Z2h bf16 (12.6MB) | WTk|WTq|WTv|WoT bf16 (4.7MB)
// ---------------------------------------------------------------------------
extern "C" void kernel_launch(void* const* d_in, const int* in_sizes, int n_in,
                              void* d_out, int out_size, void* d_ws, size_t ws_size,
                              hipStream_t stream)
{
    const float* Xk = (const float*)d_in[0];
    const float* Xv = (const float*)d_in[1];
    const float* Xq = (const float*)d_in[2];
    const float* Wk = (const float*)d_in[3];
    const float* Wq = (const float*)d_in[4];
    const float* Wv = (const float*)d_in[5];
    const float* Wo = (const float*)d_in[6];
    const float* bo = (const float*)d_in[7];
    float* out = (float*)d_out;

    const size_t phd = (size_t)B_ * H_ * T_ * D_;   // 6,291,456
    const size_t wsz = (size_t)H_ * E_ * D_;        // 589,824
    float* Kp = (float*)d_ws;
    float* Vp = Kp + phd;
    float* Qp = Vp + phd;
    unsigned short* Z2h = (unsigned short*)(Qp + phd);   // B*T*E bf16
    unsigned short* WTk = Z2h + (size_t)B_ * T_ * E_;
    unsigned short* WTq = WTk + wsz;
    unsigned short* WTv = WTq + wsz;
    unsigned short* WoT = WTv + wsz;                     // E*E bf16

    dim3 blk(256);

    // Weights -> bf16, transposed to [N][K]
    dim3 gtw(D_ / 32, E_ / 32, H_);                 // (8, 24, 3)
    transpose_cast<<<gtw, blk, 0, stream>>>(Wk, WTk, E_, D_);
    transpose_cast<<<gtw, blk, 0, stream>>>(Wq, WTq, E_, D_);
    transpose_cast<<<gtw, blk, 0, stream>>>(Wv, WTv, E_, D_);
    dim3 gto(E_ / 32, E_ / 32, 1);                  // (24, 24, 1)
    transpose_cast<<<gto, blk, 0, stream>>>(Wo, WoT, E_, E_);

    // Projections (fused fp32->bf16 A-staging): [T,E] x [E,D] -> [B,H,T,D] fp32
    dim3 gproj(D_ / 128, T_ / 128, B_ * H_);        // (2, 16, 12)
    gemm_mfma<true><<<gproj, blk, 0, stream>>>(Xk, WTk, Kp, nullptr, E_, H_, E_, D_,
                                               (long)T_ * E_, (long)D_ * E_, (long)T_ * D_);
    gemm_mfma<true><<<gproj, blk, 0, stream>>>(Xv, WTv, Vp, nullptr, E_, H_, E_, D_,
                                               (long)T_ * E_, (long)D_ * E_, (long)T_ * D_);
    gemm_mfma<true><<<gproj, blk, 0, stream>>>(Xq, WTq, Qp, nullptr, E_, H_, E_, D_,
                                               (long)T_ * E_, (long)D_ * E_, (long)T_ * D_);

    // Causal flash attention -> Z2h bf16 [B, T, H*D]
    dim3 gf(T_ / 32, B_ * H_);
    flash32<<<gf, blk, 0, stream>>>(Qp, Kp, Vp, Z2h, 0.022097086912079608f /* 1/sqrt(2048) */);

    // Output projection: [B*T, E] x [E, E] + bo -> out fp32
    dim3 gout(E_ / 128, (B_ * T_) / 128, 1);        // (6, 64, 1)
    gemm_mfma<false><<<gout, blk, 0, stream>>>(Z2h, WoT, out, bo, E_, 1, E_, E_,
                                               0L, 0L, 0L);
}

// Round 6
// 589.500 us; speedup vs baseline: 4.0086x; 2.7611x over previous
//
#include <hip/hip_runtime.h>
#include <hip/hip_bf16.h>
#include <math.h>

#define B_ 4
#define T_ 2048
#define E_ 768
#define H_ 3
#define D_ 256
#define LOG2E 1.4426950408889634f

typedef __attribute__((ext_vector_type(8))) _Float16 half8;
typedef __attribute__((ext_vector_type(8))) unsigned short ushort8;
typedef __attribute__((ext_vector_type(4))) float f32x4;

static __device__ inline unsigned short f2h(float x) {
    _Float16 h = (_Float16)x;
    return *reinterpret_cast<unsigned short*>(&h);
}

// ---------------------------------------------------------------------------
// Transpose + fp32->fp16 cast: in [z][R][C] fp32 -> out [z][C][R] fp16.
// (Weights -> [N][K] so GEMM B-tiles are k-contiguous.)
// ---------------------------------------------------------------------------
__global__ __launch_bounds__(256)
void transpose_cast(const float* __restrict__ in, unsigned short* __restrict__ out,
                    int R, int Ccols)
{
    __shared__ float tile[32][33];
    const long zoff = (long)blockIdx.z * R * Ccols;
    const int c0 = blockIdx.x * 32;
    const int r0 = blockIdx.y * 32;
    const int t  = threadIdx.x;
    const int cc = t & 31, rr = t >> 5;
    #pragma unroll
    for (int i = 0; i < 4; ++i)
        tile[rr + i * 8][cc] = in[zoff + (long)(r0 + rr + i * 8) * Ccols + c0 + cc];
    __syncthreads();
    const int rr2 = t & 31, cc2 = t >> 5;
    #pragma unroll
    for (int i = 0; i < 4; ++i)
        out[zoff + (long)(c0 + cc2 + i * 8) * R + r0 + rr2] = f2h(tile[rr2][cc2 + i * 8]);
}

// ---------------------------------------------------------------------------
// fp16 transpose: in [z][R][C] f16 -> out [z][C][R] f16. 64x64 tiles.
// LDS rows 128B with XOR swizzle key ((row>>3)&7)<<4: write = 8 rows x 8
// xor'd 16B slots (uniform banks); read = scalar b16, bank = (cc>>1) ^
// (4*(row>>3)) -> 32 distinct banks x dword-pairs. Conflict-free both ways.
// ---------------------------------------------------------------------------
__global__ __launch_bounds__(256)
void transpose16(const unsigned short* __restrict__ in, unsigned short* __restrict__ out,
                 int R, int Ccols)
{
    __shared__ unsigned short tile[64 * 64];
    char* tb = (char*)tile;
    const long zoff = (long)blockIdx.z * R * Ccols;
    const int r0 = blockIdx.y * 64, c0 = blockIdx.x * 64;
    const int t = threadIdx.x;
    #pragma unroll
    for (int i = 0; i < 2; ++i) {
        const int rr = (t >> 3) + i * 32;
        const int gc = (t & 7) * 8;
        ushort8 v = *(const ushort8*)(in + zoff + (long)(r0 + rr) * Ccols + c0 + gc);
        *(ushort8*)(tb + rr * 128 + ((gc * 2) ^ (((rr >> 3) & 7) << 4))) = v;
    }
    __syncthreads();
    #pragma unroll
    for (int i = 0; i < 2; ++i) {
        const int cc = (t >> 3) + i * 32;     // output row (= input col)
        const int gr = (t & 7) * 8;           // input-row granule
        ushort8 v;
        #pragma unroll
        for (int e = 0; e < 8; ++e) {
            const int row = gr + e;
            v[e] = *(const unsigned short*)(tb + row * 128 + ((cc * 2) ^ (((row >> 3) & 7) << 4)));
        }
        *(ushort8*)(out + zoff + (long)(c0 + cc) * R + r0 + gr) = v;
    }
}

// ---------------------------------------------------------------------------
// fp16 MFMA GEMM: C[M,N] = A[M,K] * B^T (Bt as [N][K] f16). Tile 128x128,
// BK=32, 4 waves (2x2 of 64x64). A fp32 (CONVA: fused cast) or f16.
// OUT16: write f16, else fp32 (+bias). Same structure as validated R5 GEMM.
// ---------------------------------------------------------------------------
template<bool CONVA, bool OUT16>
__global__ __launch_bounds__(256)
void gemm_mfma(const void* __restrict__ Av, const unsigned short* __restrict__ Bt,
               void* __restrict__ Cv, const float* __restrict__ bias,
               int K, int Hdiv, int lda, int ldc, long sA, long sB, long sC)
{
    __shared__ unsigned short As[128 * 32];
    __shared__ unsigned short Bs[128 * 32];

    const int z = blockIdx.z;
    const float*          Af = (const float*)Av          + (long)(z / Hdiv) * sA;
    const unsigned short* Ah = (const unsigned short*)Av + (long)(z / Hdiv) * sA;
    const unsigned short* Bz = Bt + (long)(z % Hdiv) * sB;

    const int m0 = blockIdx.y * 128, n0 = blockIdx.x * 128;
    const int tid  = threadIdx.x;
    const int lane = tid & 63, wid = tid >> 6;
    const int wm = wid >> 1, wn = wid & 1;
    const int fr = lane & 15, fg = lane >> 4;

    f32x4 acc[4][4];
    #pragma unroll
    for (int mt = 0; mt < 4; ++mt)
        #pragma unroll
        for (int nt = 0; nt < 4; ++nt) acc[mt][nt] = (f32x4)(0.f);

    for (int k0 = 0; k0 < K; k0 += 32) {
        #pragma unroll
        for (int i = 0; i < 2; ++i) {
            const int G = tid + i * 256;
            const int row = G >> 2, g = G & 3;
            ushort8 pa;
            if (CONVA) {
                const float* s = Af + (long)(m0 + row) * lda + k0 + g * 8;
                float4 f0 = *(const float4*)s, f1 = *(const float4*)(s + 4);
                pa[0] = f2h(f0.x); pa[1] = f2h(f0.y); pa[2] = f2h(f0.z); pa[3] = f2h(f0.w);
                pa[4] = f2h(f1.x); pa[5] = f2h(f1.y); pa[6] = f2h(f1.z); pa[7] = f2h(f1.w);
            } else {
                pa = *(const ushort8*)(Ah + (long)(m0 + row) * lda + k0 + g * 8);
            }
            *(ushort8*)&As[row * 32 + g * 8] = pa;
            *(ushort8*)&Bs[row * 32 + g * 8] =
                *(const ushort8*)(Bz + (long)(n0 + row) * K + k0 + g * 8);
        }
        __syncthreads();

        half8 a[4], b[4];
        #pragma unroll
        for (int mt = 0; mt < 4; ++mt)
            a[mt] = *(const half8*)&As[(wm * 64 + mt * 16 + fr) * 32 + fg * 8];
        #pragma unroll
        for (int nt = 0; nt < 4; ++nt)
            b[nt] = *(const half8*)&Bs[(wn * 64 + nt * 16 + fr) * 32 + fg * 8];
        #pragma unroll
        for (int mt = 0; mt < 4; ++mt)
            #pragma unroll
            for (int nt = 0; nt < 4; ++nt)
                acc[mt][nt] = __builtin_amdgcn_mfma_f32_16x16x32_f16(
                                  a[mt], b[nt], acc[mt][nt], 0, 0, 0);
        __syncthreads();
    }

    #pragma unroll
    for (int nt = 0; nt < 4; ++nt) {
        const int col = n0 + wn * 64 + nt * 16 + fr;
        const float badd = bias ? bias[col] : 0.f;
        #pragma unroll
        for (int mt = 0; mt < 4; ++mt) {
            const int row = m0 + wm * 64 + mt * 16 + fg * 4;
            #pragma unroll
            for (int reg = 0; reg < 4; ++reg) {
                if (OUT16)
                    ((unsigned short*)Cv)[(long)z * sC + (long)(row + reg) * ldc + col] =
                        f2h(acc[mt][nt][reg] + badd);
                else
                    ((float*)Cv)[(long)z * sC + (long)(row + reg) * ldc + col] =
                        acc[mt][nt][reg] + badd;
            }
        }
    }
}

// ---------------------------------------------------------------------------
// MFMA causal flash attention, f16 in / fp32 softmax+accum / f16 out.
// Q,K: [B*H][T][D] f16; Vt: [B*H][D][T] f16; out Z2h: [B][T][H*D] f16.
// Block = 64 q-rows, 4 waves (16 rows each); K-tiles of 64.
// Ks [64][264] (row-bank rotation 4*fr: conflict-free b128 B-frag reads);
// Vts [256][72] (same rotation); Ps per-wave [16][72] f16.
// mfma_f32_16x16x32_f16 layouts (m89/m91-verified family):
//   A: row=lane&15, k=(lane>>4)*8+e  -> k-contiguous 16B reads
//   B: col=lane&15, k=(lane>>4)*8+e  -> operand stored [col][k]
//   C/D: col=lane&15, row=(lane>>4)*4+reg
// ---------------------------------------------------------------------------
__global__ __launch_bounds__(256)
void flash_mfma(const unsigned short* __restrict__ Qb, const unsigned short* __restrict__ Kb,
                const unsigned short* __restrict__ Vtb, unsigned short* __restrict__ Z2h,
                float scale)
{
    __shared__ unsigned short Ks[64 * 264];
    __shared__ unsigned short Vts[256 * 72];
    __shared__ unsigned short Ps[4][16 * 72];

    const int bh = blockIdx.y, b = bh / H_, h = bh % H_;
    const int q0 = (int)(gridDim.x - 1 - blockIdx.x) * 64;   // heavy blocks first
    const int tid = threadIdx.x, lane = tid & 63, w = tid >> 6;
    const int g = lane >> 4, fr = lane & 15;

    // Q fragments for this wave's 16-row strip (rows q0+w*16 .. +15)
    const unsigned short* qrow = Qb + ((long)bh * T_ + q0 + w * 16 + fr) * D_;
    half8 qf[8];
    #pragma unroll
    for (int c = 0; c < 8; ++c)
        qf[c] = *(const half8*)(qrow + c * 32 + g * 8);

    f32x4 o[16];
    #pragma unroll
    for (int dt = 0; dt < 16; ++dt) o[dt] = (f32x4)(0.f);
    float mrow[4] = {-INFINITY, -INFINITY, -INFINITY, -INFINITY};
    float lrow[4] = {0.f, 0.f, 0.f, 0.f};

    const int nkt = q0 / 64 + 1;
    for (int kt = 0; kt < nkt; ++kt) {
        const int k0 = kt * 64;
        // ---- stage K tile [64][256] and Vt tile [256][64] ----
        const unsigned short* ksrc = Kb + ((long)bh * T_ + k0) * D_;
        #pragma unroll
        for (int i = 0; i < 8; ++i) {
            const int L = tid + i * 256, r = L >> 5, c8 = (L & 31) * 8;
            *(ushort8*)&Ks[r * 264 + c8] = *(const ushort8*)(ksrc + (long)r * D_ + c8);
        }
        const unsigned short* vsrc = Vtb + (long)bh * D_ * T_ + k0;
        #pragma unroll
        for (int i = 0; i < 8; ++i) {
            const int L = tid + i * 256, r = L >> 3, c8 = (L & 7) * 8;
            *(ushort8*)&Vts[r * 72 + c8] = *(const ushort8*)(vsrc + (long)r * T_ + c8);
        }
        __syncthreads();

        // ---- QK^T: S[16q x 64k] per wave ----
        f32x4 s[4];
        #pragma unroll
        for (int nt = 0; nt < 4; ++nt) s[nt] = (f32x4)(0.f);
        #pragma unroll
        for (int nt = 0; nt < 4; ++nt)
            #pragma unroll
            for (int c = 0; c < 8; ++c) {
                half8 kf = *(const half8*)&Ks[(nt * 16 + fr) * 264 + c * 32 + g * 8];
                s[nt] = __builtin_amdgcn_mfma_f32_16x16x32_f16(qf[c], kf, s[nt], 0, 0, 0);
            }

        // ---- scale + causal mask (diag tile only) ----
        const bool diag = (kt == nkt - 1);
        float sv[4][4];
        #pragma unroll
        for (int nt = 0; nt < 4; ++nt)
            #pragma unroll
            for (int reg = 0; reg < 4; ++reg) {
                float v = s[nt][reg] * scale;
                if (diag && (fr + nt * 16 > w * 16 + g * 4 + reg)) v = -INFINITY;
                sv[nt][reg] = v;
            }

        // ---- online softmax (rows live on 16-lane groups) ----
        float alpha[4], psum[4];
        #pragma unroll
        for (int reg = 0; reg < 4; ++reg) {
            float tm = fmaxf(fmaxf(sv[0][reg], sv[1][reg]), fmaxf(sv[2][reg], sv[3][reg]));
            tm = fmaxf(tm, __shfl_xor(tm, 1));
            tm = fmaxf(tm, __shfl_xor(tm, 2));
            tm = fmaxf(tm, __shfl_xor(tm, 4));
            tm = fmaxf(tm, __shfl_xor(tm, 8));
            const float mnew = fmaxf(mrow[reg], tm);
            alpha[reg] = exp2f((mrow[reg] - mnew) * LOG2E);
            mrow[reg] = mnew;
            psum[reg] = 0.f;
        }
        #pragma unroll
        for (int nt = 0; nt < 4; ++nt)
            #pragma unroll
            for (int reg = 0; reg < 4; ++reg) {
                const float p = exp2f((sv[nt][reg] - mrow[reg]) * LOG2E);
                psum[reg] += p;
                Ps[w][(g * 4 + reg) * 72 + fr + nt * 16] = f2h(p);
            }
        #pragma unroll
        for (int reg = 0; reg < 4; ++reg) {
            float ps = psum[reg];
            ps += __shfl_xor(ps, 1);
            ps += __shfl_xor(ps, 2);
            ps += __shfl_xor(ps, 4);
            ps += __shfl_xor(ps, 8);
            lrow[reg] = lrow[reg] * alpha[reg] + ps;
        }
        #pragma unroll
        for (int dt = 0; dt < 16; ++dt)
            #pragma unroll
            for (int reg = 0; reg < 4; ++reg) o[dt][reg] *= alpha[reg];

        asm volatile("s_waitcnt lgkmcnt(0)" ::: "memory");

        // ---- PV: O[16q x 256d] += P[16q x 64k] * V[64k x 256d] ----
        const half8 pf0 = *(const half8*)&Ps[w][fr * 72 + g * 8];
        const half8 pf1 = *(const half8*)&Ps[w][fr * 72 + 32 + g * 8];
        #pragma unroll
        for (int dt = 0; dt < 16; ++dt) {
            half8 vf0 = *(const half8*)&Vts[(dt * 16 + fr) * 72 + g * 8];
            o[dt] = __builtin_amdgcn_mfma_f32_16x16x32_f16(pf0, vf0, o[dt], 0, 0, 0);
            half8 vf1 = *(const half8*)&Vts[(dt * 16 + fr) * 72 + 32 + g * 8];
            o[dt] = __builtin_amdgcn_mfma_f32_16x16x32_f16(pf1, vf1, o[dt], 0, 0, 0);
        }
        __syncthreads();
    }

    // ---- epilogue: O /= l, write f16 into [B][T][H*D] ----
    float inv[4];
    #pragma unroll
    for (int reg = 0; reg < 4; ++reg) inv[reg] = 1.f / lrow[reg];
    const long rowbase = ((long)b * T_ + q0 + w * 16 + g * 4) * E_ + h * D_;
    #pragma unroll
    for (int reg = 0; reg < 4; ++reg) {
        unsigned short* dst = Z2h + rowbase + (long)reg * E_ + fr;
        #pragma unroll
        for (int dt = 0; dt < 16; ++dt)
            dst[dt * 16] = f2h(o[dt][reg] * inv[reg]);
    }
}

// ---------------------------------------------------------------------------
// d_in: keys, values, queries, Wk, Wq, Wv, Wo, bo (fp32)
// ws (f16): Kp|Vp|Qp|Vt (4 x 12.6MB) | Z2h 12.6MB | WTk|WTq|WTv|WoT 4.7MB
// ---------------------------------------------------------------------------
extern "C" void kernel_launch(void* const* d_in, const int* in_sizes, int n_in,
                              void* d_out, int out_size, void* d_ws, size_t ws_size,
                              hipStream_t stream)
{
    const float* Xk = (const float*)d_in[0];
    const float* Xv = (const float*)d_in[1];
    const float* Xq = (const float*)d_in[2];
    const float* Wk = (const float*)d_in[3];
    const float* Wq = (const float*)d_in[4];
    const float* Wv = (const float*)d_in[5];
    const float* Wo = (const float*)d_in[6];
    const float* bo = (const float*)d_in[7];
    float* out = (float*)d_out;

    const size_t phd = (size_t)B_ * H_ * T_ * D_;   // 6,291,456
    const size_t wsz = (size_t)H_ * E_ * D_;        // 589,824
    unsigned short* Kp  = (unsigned short*)d_ws;
    unsigned short* Vp  = Kp + phd;
    unsigned short* Qp  = Vp + phd;
    unsigned short* Vt  = Qp + phd;
    unsigned short* Z2h = Vt + phd;
    unsigned short* WTk = Z2h + (size_t)B_ * T_ * E_;
    unsigned short* WTq = WTk + wsz;
    unsigned short* WTv = WTq + wsz;
    unsigned short* WoT = WTv + wsz;

    dim3 blk(256);

    // Weights -> f16, [N][K]
    dim3 gtw(D_ / 32, E_ / 32, H_);
    transpose_cast<<<gtw, blk, 0, stream>>>(Wk, WTk, E_, D_);
    transpose_cast<<<gtw, blk, 0, stream>>>(Wq, WTq, E_, D_);
    transpose_cast<<<gtw, blk, 0, stream>>>(Wv, WTv, E_, D_);
    dim3 gto(E_ / 32, E_ / 32, 1);
    transpose_cast<<<gto, blk, 0, stream>>>(Wo, WoT, E_, E_);

    // Projections: fp32 X * f16 W -> f16 [B,H,T,D]
    dim3 gproj(D_ / 128, T_ / 128, B_ * H_);
    gemm_mfma<true, true><<<gproj, blk, 0, stream>>>(Xk, WTk, Kp, nullptr, E_, H_, E_, D_,
                                                     (long)T_ * E_, (long)D_ * E_, (long)T_ * D_);
    gemm_mfma<true, true><<<gproj, blk, 0, stream>>>(Xv, WTv, Vp, nullptr, E_, H_, E_, D_,
                                                     (long)T_ * E_, (long)D_ * E_, (long)T_ * D_);
    gemm_mfma<true, true><<<gproj, blk, 0, stream>>>(Xq, WTq, Qp, nullptr, E_, H_, E_, D_,
                                                     (long)T_ * E_, (long)D_ * E_, (long)T_ * D_);

    // V -> Vt [B*H][D][T]
    dim3 gtv(D_ / 64, T_ / 64, B_ * H_);
    transpose16<<<gtv, blk, 0, stream>>>(Vp, Vt, T_, D_);

    // MFMA causal flash attention -> Z2h f16 [B][T][H*D]
    dim3 gf(T_ / 64, B_ * H_);
    flash_mfma<<<gf, blk, 0, stream>>>(Qp, Kp, Vt, Z2h, 0.022097086912079608f /* 1/sqrt(2048) */);

    // Output projection: f16 Z * f16 Wo + bo -> fp32 out
    dim3 gout(E_ / 128, (B_ * T_) / 128, 1);
    gemm_mfma<false, false><<<gout, blk, 0, stream>>>(Z2h, WoT, out, bo, E_, 1, E_, E_,
                                                      0L, 0L, 0L);
}

// Round 7
// 429.395 us; speedup vs baseline: 5.5033x; 1.3729x over previous
//
#include <hip/hip_runtime.h>
#include <hip/hip_bf16.h>
#include <math.h>

#define B_ 4
#define T_ 2048
#define E_ 768
#define H_ 3
#define D_ 256
#define LOG2E 1.4426950408889634f

typedef __attribute__((ext_vector_type(8))) _Float16 half8;
typedef __attribute__((ext_vector_type(8))) unsigned short ushort8;
typedef __attribute__((ext_vector_type(4))) float f32x4;

static __device__ inline unsigned short f2h(float x) {
    _Float16 h = (_Float16)x;
    return *reinterpret_cast<unsigned short*>(&h);
}

// ---------------------------------------------------------------------------
// Transpose + fp32->fp16 cast: in [z][R][C] fp32 -> out [z][C][R] fp16.
// ---------------------------------------------------------------------------
__global__ __launch_bounds__(256)
void transpose_cast(const float* __restrict__ in, unsigned short* __restrict__ out,
                    int R, int Ccols)
{
    __shared__ float tile[32][33];
    const long zoff = (long)blockIdx.z * R * Ccols;
    const int c0 = blockIdx.x * 32;
    const int r0 = blockIdx.y * 32;
    const int t  = threadIdx.x;
    const int cc = t & 31, rr = t >> 5;
    #pragma unroll
    for (int i = 0; i < 4; ++i)
        tile[rr + i * 8][cc] = in[zoff + (long)(r0 + rr + i * 8) * Ccols + c0 + cc];
    __syncthreads();
    const int rr2 = t & 31, cc2 = t >> 5;
    #pragma unroll
    for (int i = 0; i < 4; ++i)
        out[zoff + (long)(c0 + cc2 + i * 8) * R + r0 + rr2] = f2h(tile[rr2][cc2 + i * 8]);
}

// ---------------------------------------------------------------------------
// fp16 transpose: in [z][R][C] f16 -> out [z][C][R] f16. 64x64 tiles,
// XOR-swizzled LDS (conflict-free both phases). (Validated R6.)
// ---------------------------------------------------------------------------
__global__ __launch_bounds__(256)
void transpose16(const unsigned short* __restrict__ in, unsigned short* __restrict__ out,
                 int R, int Ccols)
{
    __shared__ unsigned short tile[64 * 64];
    char* tb = (char*)tile;
    const long zoff = (long)blockIdx.z * R * Ccols;
    const int r0 = blockIdx.y * 64, c0 = blockIdx.x * 64;
    const int t = threadIdx.x;
    #pragma unroll
    for (int i = 0; i < 2; ++i) {
        const int rr = (t >> 3) + i * 32;
        const int gc = (t & 7) * 8;
        ushort8 v = *(const ushort8*)(in + zoff + (long)(r0 + rr) * Ccols + c0 + gc);
        *(ushort8*)(tb + rr * 128 + ((gc * 2) ^ (((rr >> 3) & 7) << 4))) = v;
    }
    __syncthreads();
    #pragma unroll
    for (int i = 0; i < 2; ++i) {
        const int cc = (t >> 3) + i * 32;
        const int gr = (t & 7) * 8;
        ushort8 v;
        #pragma unroll
        for (int e = 0; e < 8; ++e) {
            const int row = gr + e;
            v[e] = *(const unsigned short*)(tb + row * 128 + ((cc * 2) ^ (((row >> 3) & 7) << 4)));
        }
        *(ushort8*)(out + zoff + (long)(c0 + cc) * R + r0 + gr) = v;
    }
}

// ---------------------------------------------------------------------------
// fp16 MFMA GEMM (validated R6): C[M,N] = A[M,K] * B^T, tile 128x128, BK=32.
// ---------------------------------------------------------------------------
template<bool CONVA, bool OUT16>
__global__ __launch_bounds__(256)
void gemm_mfma(const void* __restrict__ Av, const unsigned short* __restrict__ Bt,
               void* __restrict__ Cv, const float* __restrict__ bias,
               int K, int Hdiv, int lda, int ldc, long sA, long sB, long sC)
{
    __shared__ unsigned short As[128 * 32];
    __shared__ unsigned short Bs[128 * 32];

    const int z = blockIdx.z;
    const float*          Af = (const float*)Av          + (long)(z / Hdiv) * sA;
    const unsigned short* Ah = (const unsigned short*)Av + (long)(z / Hdiv) * sA;
    const unsigned short* Bz = Bt + (long)(z % Hdiv) * sB;

    const int m0 = blockIdx.y * 128, n0 = blockIdx.x * 128;
    const int tid  = threadIdx.x;
    const int lane = tid & 63, wid = tid >> 6;
    const int wm = wid >> 1, wn = wid & 1;
    const int fr = lane & 15, fg = lane >> 4;

    f32x4 acc[4][4];
    #pragma unroll
    for (int mt = 0; mt < 4; ++mt)
        #pragma unroll
        for (int nt = 0; nt < 4; ++nt) acc[mt][nt] = (f32x4)(0.f);

    for (int k0 = 0; k0 < K; k0 += 32) {
        #pragma unroll
        for (int i = 0; i < 2; ++i) {
            const int G = tid + i * 256;
            const int row = G >> 2, g = G & 3;
            ushort8 pa;
            if (CONVA) {
                const float* s = Af + (long)(m0 + row) * lda + k0 + g * 8;
                float4 f0 = *(const float4*)s, f1 = *(const float4*)(s + 4);
                pa[0] = f2h(f0.x); pa[1] = f2h(f0.y); pa[2] = f2h(f0.z); pa[3] = f2h(f0.w);
                pa[4] = f2h(f1.x); pa[5] = f2h(f1.y); pa[6] = f2h(f1.z); pa[7] = f2h(f1.w);
            } else {
                pa = *(const ushort8*)(Ah + (long)(m0 + row) * lda + k0 + g * 8);
            }
            *(ushort8*)&As[row * 32 + g * 8] = pa;
            *(ushort8*)&Bs[row * 32 + g * 8] =
                *(const ushort8*)(Bz + (long)(n0 + row) * K + k0 + g * 8);
        }
        __syncthreads();

        half8 a[4], b[4];
        #pragma unroll
        for (int mt = 0; mt < 4; ++mt)
            a[mt] = *(const half8*)&As[(wm * 64 + mt * 16 + fr) * 32 + fg * 8];
        #pragma unroll
        for (int nt = 0; nt < 4; ++nt)
            b[nt] = *(const half8*)&Bs[(wn * 64 + nt * 16 + fr) * 32 + fg * 8];
        #pragma unroll
        for (int mt = 0; mt < 4; ++mt)
            #pragma unroll
            for (int nt = 0; nt < 4; ++nt)
                acc[mt][nt] = __builtin_amdgcn_mfma_f32_16x16x32_f16(
                                  a[mt], b[nt], acc[mt][nt], 0, 0, 0);
        __syncthreads();
    }

    #pragma unroll
    for (int nt = 0; nt < 4; ++nt) {
        const int col = n0 + wn * 64 + nt * 16 + fr;
        const float badd = bias ? bias[col] : 0.f;
        #pragma unroll
        for (int mt = 0; mt < 4; ++mt) {
            const int row = m0 + wm * 64 + mt * 16 + fg * 4;
            #pragma unroll
            for (int reg = 0; reg < 4; ++reg) {
                if (OUT16)
                    ((unsigned short*)Cv)[(long)z * sC + (long)(row + reg) * ldc + col] =
                        f2h(acc[mt][nt][reg] + badd);
                else
                    ((float*)Cv)[(long)z * sC + (long)(row + reg) * ldc + col] =
                        acc[mt][nt][reg] + badd;
            }
        }
    }
}

// ---------------------------------------------------------------------------
// Streaming MFMA causal flash attention. ONE WAVE PER BLOCK, 16 q-rows.
// No __syncthreads, no K/V LDS staging: K [bh][T][D] and Vt [bh][D][T] frags
// are read straight from global (L2/LLC-resident; per-lane 16B contiguous).
// Grid 1536 = 128 qtiles x 12 bh, XCD-chunked (l=(p&7)*192+p/8) so each
// XCD's 192 blocks touch <=2 bh -> K+Vt working set ~4MB fits its L2;
// heavy/light q-tiles interleaved within each chunk for balance.
// Q pre-scaled by scale*log2e -> softmax in exp2 domain.
// Per-wave P-transpose via 2.3KB LDS (write C-layout, read A-layout).
// mfma_f32_16x16x32_f16: A row=lane&15,k=(lane>>4)*8+e; B col=lane&15,same k;
// C/D col=lane&15, row=(lane>>4)*4+reg.
// ---------------------------------------------------------------------------
__global__ __launch_bounds__(64, 2)
void flash_stream(const unsigned short* __restrict__ Qb, const unsigned short* __restrict__ Kb,
                  const unsigned short* __restrict__ Vtb, unsigned short* __restrict__ Z2h,
                  float scale_log2e)
{
    __shared__ unsigned short Ps[16 * 72];

    const int p  = blockIdx.x;
    const int l  = (p & 7) * 192 + (p >> 3);      // XCD chunking (bijective, 1536=8*192)
    const int bh = l >> 7;
    const int j  = l & 127;
    const int qt = (j & 1) ? (127 - (j >> 1)) : (j >> 1);   // heavy/light interleave
    const int b = bh / H_, h = bh % H_;
    const int lane = threadIdx.x & 63;
    const int g = lane >> 4, fr = lane & 15;

    // Q fragments for rows qt*16 .. +15, pre-scaled into exp2 domain
    const unsigned short* qrow = Qb + ((long)bh * T_ + qt * 16 + fr) * D_;
    const _Float16 hs = (_Float16)scale_log2e;
    half8 qf[8];
    #pragma unroll
    for (int c = 0; c < 8; ++c) {
        qf[c] = *(const half8*)(qrow + c * 32 + g * 8);
        qf[c] *= hs;
    }

    f32x4 o[16];
    #pragma unroll
    for (int dt = 0; dt < 16; ++dt) o[dt] = (f32x4)(0.f);
    float mrow[4] = {-INFINITY, -INFINITY, -INFINITY, -INFINITY};
    float lrow[4] = {0.f, 0.f, 0.f, 0.f};

    const unsigned short* kbase = Kb  + (long)bh * T_ * D_;
    const unsigned short* vbase = Vtb + (long)bh * D_ * T_;
    const int nkt = (qt >> 2) + 1;
    const int rel = (qt & 3) * 16;                // q-row offset inside last k-tile

    for (int kt = 0; kt < nkt; ++kt) {
        const int k0 = kt * 64;

        // ---- QK^T: S[16q x 64k], B-frags streamed from K ----
        f32x4 s[4];
        #pragma unroll
        for (int nt = 0; nt < 4; ++nt) s[nt] = (f32x4)(0.f);
        const unsigned short* kp = kbase + (long)k0 * D_ + g * 8;
        __builtin_amdgcn_s_setprio(1);
        #pragma unroll
        for (int nt = 0; nt < 4; ++nt) {
            const unsigned short* kr = kp + (long)(nt * 16 + fr) * D_;
            #pragma unroll
            for (int c = 0; c < 8; ++c)
                s[nt] = __builtin_amdgcn_mfma_f32_16x16x32_f16(
                            qf[c], *(const half8*)(kr + c * 32), s[nt], 0, 0, 0);
        }
        __builtin_amdgcn_s_setprio(0);

        // ---- causal mask (last tile only), values already in log2 domain ----
        const bool diag = (kt == nkt - 1);
        float sv[4][4];
        #pragma unroll
        for (int nt = 0; nt < 4; ++nt)
            #pragma unroll
            for (int reg = 0; reg < 4; ++reg) {
                float v = s[nt][reg];
                if (diag && (nt * 16 + fr > rel + g * 4 + reg)) v = -INFINITY;
                sv[nt][reg] = v;
            }

        // ---- online softmax (rows on 16-lane groups), exp2 domain ----
        float alpha[4], psum[4];
        #pragma unroll
        for (int reg = 0; reg < 4; ++reg) {
            float tm = fmaxf(fmaxf(sv[0][reg], sv[1][reg]), fmaxf(sv[2][reg], sv[3][reg]));
            tm = fmaxf(tm, __shfl_xor(tm, 1));
            tm = fmaxf(tm, __shfl_xor(tm, 2));
            tm = fmaxf(tm, __shfl_xor(tm, 4));
            tm = fmaxf(tm, __shfl_xor(tm, 8));
            const float mnew = fmaxf(mrow[reg], tm);
            alpha[reg] = exp2f(mrow[reg] - mnew);
            mrow[reg] = mnew;
            psum[reg] = 0.f;
        }
        #pragma unroll
        for (int nt = 0; nt < 4; ++nt)
            #pragma unroll
            for (int reg = 0; reg < 4; ++reg) {
                const float pp = exp2f(sv[nt][reg] - mrow[reg]);
                psum[reg] += pp;
                Ps[(g * 4 + reg) * 72 + nt * 16 + fr] = f2h(pp);   // C-layout -> LDS
            }
        #pragma unroll
        for (int reg = 0; reg < 4; ++reg) {
            float ps = psum[reg];
            ps += __shfl_xor(ps, 1);
            ps += __shfl_xor(ps, 2);
            ps += __shfl_xor(ps, 4);
            ps += __shfl_xor(ps, 8);
            lrow[reg] = lrow[reg] * alpha[reg] + ps;
        }
        #pragma unroll
        for (int dt = 0; dt < 16; ++dt)
            #pragma unroll
            for (int reg = 0; reg < 4; ++reg) o[dt][reg] *= alpha[reg];

        // ---- P back as A-frags (wave-private LDS; compiler orders ds ops) ----
        const half8 pf0 = *(const half8*)&Ps[fr * 72 + g * 8];
        const half8 pf1 = *(const half8*)&Ps[fr * 72 + 32 + g * 8];

        // ---- PV: O[16q x 256d] += P * V, B-frags streamed from Vt ----
        const unsigned short* vp = vbase + k0 + g * 8;
        __builtin_amdgcn_s_setprio(1);
        #pragma unroll
        for (int dt = 0; dt < 16; ++dt) {
            const unsigned short* vr = vp + (long)(dt * 16 + fr) * T_;
            o[dt] = __builtin_amdgcn_mfma_f32_16x16x32_f16(pf0, *(const half8*)vr, o[dt], 0, 0, 0);
            o[dt] = __builtin_amdgcn_mfma_f32_16x16x32_f16(pf1, *(const half8*)(vr + 32), o[dt], 0, 0, 0);
        }
        __builtin_amdgcn_s_setprio(0);
    }

    // ---- epilogue: O /= l, write f16 into [B][T][H*D] ----
    float inv[4];
    #pragma unroll
    for (int reg = 0; reg < 4; ++reg) inv[reg] = 1.f / lrow[reg];
    const long rowbase = ((long)b * T_ + qt * 16 + g * 4) * E_ + h * D_;
    #pragma unroll
    for (int reg = 0; reg < 4; ++reg) {
        unsigned short* dst = Z2h + rowbase + (long)reg * E_ + fr;
        #pragma unroll
        for (int dt = 0; dt < 16; ++dt)
            dst[dt * 16] = f2h(o[dt][reg] * inv[reg]);
    }
}

// ---------------------------------------------------------------------------
// d_in: keys, values, queries, Wk, Wq, Wv, Wo, bo (fp32)
// ws (f16): Kp|Vp|Qp|Vt (4 x 12.6MB) | Z2h 12.6MB | WTk|WTq|WTv|WoT 4.7MB
// ---------------------------------------------------------------------------
extern "C" void kernel_launch(void* const* d_in, const int* in_sizes, int n_in,
                              void* d_out, int out_size, void* d_ws, size_t ws_size,
                              hipStream_t stream)
{
    const float* Xk = (const float*)d_in[0];
    const float* Xv = (const float*)d_in[1];
    const float* Xq = (const float*)d_in[2];
    const float* Wk = (const float*)d_in[3];
    const float* Wq = (const float*)d_in[4];
    const float* Wv = (const float*)d_in[5];
    const float* Wo = (const float*)d_in[6];
    const float* bo = (const float*)d_in[7];
    float* out = (float*)d_out;

    const size_t phd = (size_t)B_ * H_ * T_ * D_;   // 6,291,456
    const size_t wsz = (size_t)H_ * E_ * D_;        // 589,824
    unsigned short* Kp  = (unsigned short*)d_ws;
    unsigned short* Vp  = Kp + phd;
    unsigned short* Qp  = Vp + phd;
    unsigned short* Vt  = Qp + phd;
    unsigned short* Z2h = Vt + phd;
    unsigned short* WTk = Z2h + (size_t)B_ * T_ * E_;
    unsigned short* WTq = WTk + wsz;
    unsigned short* WTv = WTq + wsz;
    unsigned short* WoT = WTv + wsz;

    dim3 blk(256);

    // Weights -> f16, [N][K]
    dim3 gtw(D_ / 32, E_ / 32, H_);
    transpose_cast<<<gtw, blk, 0, stream>>>(Wk, WTk, E_, D_);
    transpose_cast<<<gtw, blk, 0, stream>>>(Wq, WTq, E_, D_);
    transpose_cast<<<gtw, blk, 0, stream>>>(Wv, WTv, E_, D_);
    dim3 gto(E_ / 32, E_ / 32, 1);
    transpose_cast<<<gto, blk, 0, stream>>>(Wo, WoT, E_, E_);

    // Projections: fp32 X * f16 W -> f16 [B,H,T,D]
    dim3 gproj(D_ / 128, T_ / 128, B_ * H_);
    gemm_mfma<true, true><<<gproj, blk, 0, stream>>>(Xk, WTk, Kp, nullptr, E_, H_, E_, D_,
                                                     (long)T_ * E_, (long)D_ * E_, (long)T_ * D_);
    gemm_mfma<true, true><<<gproj, blk, 0, stream>>>(Xv, WTv, Vp, nullptr, E_, H_, E_, D_,
                                                     (long)T_ * E_, (long)D_ * E_, (long)T_ * D_);
    gemm_mfma<true, true><<<gproj, blk, 0, stream>>>(Xq, WTq, Qp, nullptr, E_, H_, E_, D_,
                                                     (long)T_ * E_, (long)D_ * E_, (long)T_ * D_);

    // V -> Vt [B*H][D][T]
    dim3 gtv(D_ / 64, T_ / 64, B_ * H_);
    transpose16<<<gtv, blk, 0, stream>>>(Vp, Vt, T_, D_);

    // Streaming MFMA causal flash attention -> Z2h f16 [B][T][H*D]
    dim3 gf(128 * B_ * H_);                       // 1536 one-wave blocks
    dim3 fblk(64);
    flash_stream<<<gf, fblk, 0, stream>>>(Qp, Kp, Vt, Z2h,
                                          0.022097086912079608f * LOG2E);

    // Output projection: f16 Z * f16 Wo + bo -> fp32 out
    dim3 gout(E_ / 128, (B_ * T_) / 128, 1);
    gemm_mfma<false, false><<<gout, blk, 0, stream>>>(Z2h, WoT, out, bo, E_, 1, E_, E_,
                                                      0L, 0L, 0L);
}

// Round 8
// 390.723 us; speedup vs baseline: 6.0479x; 1.0990x over previous
//
#include <hip/hip_runtime.h>
#include <hip/hip_bf16.h>
#include <math.h>

#define B_ 4
#define T_ 2048
#define E_ 768
#define H_ 3
#define D_ 256
#define LOG2E 1.4426950408889634f

typedef __attribute__((ext_vector_type(8))) _Float16 half8;
typedef __attribute__((ext_vector_type(8))) unsigned short ushort8;
typedef __attribute__((ext_vector_type(4))) unsigned short ushort4v;
typedef __attribute__((ext_vector_type(4))) float f32x4;

static __device__ inline unsigned short f2h(float x) {
    _Float16 h = (_Float16)x;
    return *reinterpret_cast<unsigned short*>(&h);
}

// ---------------------------------------------------------------------------
// Transpose + fp32->fp16 cast: in [z][R][C] fp32 -> out [z][C][R] fp16.
// ---------------------------------------------------------------------------
__global__ __launch_bounds__(256)
void transpose_cast(const float* __restrict__ in, unsigned short* __restrict__ out,
                    int R, int Ccols)
{
    __shared__ float tile[32][33];
    const long zoff = (long)blockIdx.z * R * Ccols;
    const int c0 = blockIdx.x * 32;
    const int r0 = blockIdx.y * 32;
    const int t  = threadIdx.x;
    const int cc = t & 31, rr = t >> 5;
    #pragma unroll
    for (int i = 0; i < 4; ++i)
        tile[rr + i * 8][cc] = in[zoff + (long)(r0 + rr + i * 8) * Ccols + c0 + cc];
    __syncthreads();
    const int rr2 = t & 31, cc2 = t >> 5;
    #pragma unroll
    for (int i = 0; i < 4; ++i)
        out[zoff + (long)(c0 + cc2 + i * 8) * R + r0 + rr2] = f2h(tile[rr2][cc2 + i * 8]);
}

// ---------------------------------------------------------------------------
// fp16 transpose: in [z][R][C] f16 -> out [z][C][R] f16. 64x64 tiles,
// XOR-swizzled LDS (conflict-free both phases). (Validated R6/R7.)
// ---------------------------------------------------------------------------
__global__ __launch_bounds__(256)
void transpose16(const unsigned short* __restrict__ in, unsigned short* __restrict__ out,
                 int R, int Ccols)
{
    __shared__ unsigned short tile[64 * 64];
    char* tb = (char*)tile;
    const long zoff = (long)blockIdx.z * R * Ccols;
    const int r0 = blockIdx.y * 64, c0 = blockIdx.x * 64;
    const int t = threadIdx.x;
    #pragma unroll
    for (int i = 0; i < 2; ++i) {
        const int rr = (t >> 3) + i * 32;
        const int gc = (t & 7) * 8;
        ushort8 v = *(const ushort8*)(in + zoff + (long)(r0 + rr) * Ccols + c0 + gc);
        *(ushort8*)(tb + rr * 128 + ((gc * 2) ^ (((rr >> 3) & 7) << 4))) = v;
    }
    __syncthreads();
    #pragma unroll
    for (int i = 0; i < 2; ++i) {
        const int cc = (t >> 3) + i * 32;
        const int gr = (t & 7) * 8;
        ushort8 v;
        #pragma unroll
        for (int e = 0; e < 8; ++e) {
            const int row = gr + e;
            v[e] = *(const unsigned short*)(tb + row * 128 + ((cc * 2) ^ (((row >> 3) & 7) << 4)));
        }
        *(ushort8*)(out + zoff + (long)(c0 + cc) * R + r0 + gr) = v;
    }
}

// ---------------------------------------------------------------------------
// fp16 MFMA GEMM body (validated R6/R7 structure): C = A * B^T on one z-slice.
// Tile 128x128, BK=32, 4 waves (2x2 of 64x64). Pointers pre-offset by caller.
// ---------------------------------------------------------------------------
template<bool CONVA, bool OUT16>
__device__ __forceinline__
void gemm_body(const float* Af, const unsigned short* Ah, const unsigned short* Bz,
               void* Cz, const float* bias, int K, int lda, int ldc,
               int m0, int n0, int tid)
{
    __shared__ unsigned short As[128 * 32];
    __shared__ unsigned short Bs[128 * 32];

    const int lane = tid & 63, wid = tid >> 6;
    const int wm = wid >> 1, wn = wid & 1;
    const int fr = lane & 15, fg = lane >> 4;

    f32x4 acc[4][4];
    #pragma unroll
    for (int mt = 0; mt < 4; ++mt)
        #pragma unroll
        for (int nt = 0; nt < 4; ++nt) acc[mt][nt] = (f32x4)(0.f);

    for (int k0 = 0; k0 < K; k0 += 32) {
        #pragma unroll
        for (int i = 0; i < 2; ++i) {
            const int G = tid + i * 256;
            const int row = G >> 2, g = G & 3;
            ushort8 pa;
            if (CONVA) {
                const float* s = Af + (long)(m0 + row) * lda + k0 + g * 8;
                float4 f0 = *(const float4*)s, f1 = *(const float4*)(s + 4);
                pa[0] = f2h(f0.x); pa[1] = f2h(f0.y); pa[2] = f2h(f0.z); pa[3] = f2h(f0.w);
                pa[4] = f2h(f1.x); pa[5] = f2h(f1.y); pa[6] = f2h(f1.z); pa[7] = f2h(f1.w);
            } else {
                pa = *(const ushort8*)(Ah + (long)(m0 + row) * lda + k0 + g * 8);
            }
            *(ushort8*)&As[row * 32 + g * 8] = pa;
            *(ushort8*)&Bs[row * 32 + g * 8] =
                *(const ushort8*)(Bz + (long)(n0 + row) * K + k0 + g * 8);
        }
        __syncthreads();

        half8 a[4], b[4];
        #pragma unroll
        for (int mt = 0; mt < 4; ++mt)
            a[mt] = *(const half8*)&As[(wm * 64 + mt * 16 + fr) * 32 + fg * 8];
        #pragma unroll
        for (int nt = 0; nt < 4; ++nt)
            b[nt] = *(const half8*)&Bs[(wn * 64 + nt * 16 + fr) * 32 + fg * 8];
        #pragma unroll
        for (int mt = 0; mt < 4; ++mt)
            #pragma unroll
            for (int nt = 0; nt < 4; ++nt)
                acc[mt][nt] = __builtin_amdgcn_mfma_f32_16x16x32_f16(
                                  a[mt], b[nt], acc[mt][nt], 0, 0, 0);
        __syncthreads();
    }

    #pragma unroll
    for (int nt = 0; nt < 4; ++nt) {
        const int col = n0 + wn * 64 + nt * 16 + fr;
        const float badd = bias ? bias[col] : 0.f;
        #pragma unroll
        for (int mt = 0; mt < 4; ++mt) {
            const int row = m0 + wm * 64 + mt * 16 + fg * 4;
            #pragma unroll
            for (int reg = 0; reg < 4; ++reg) {
                if (OUT16)
                    ((unsigned short*)Cz)[(long)(row + reg) * ldc + col] =
                        f2h(acc[mt][nt][reg] + badd);
                else
                    ((float*)Cz)[(long)(row + reg) * ldc + col] =
                        acc[mt][nt][reg] + badd;
            }
        }
    }
}

// Generic batched wrapper (used for output projection).
template<bool CONVA, bool OUT16>
__global__ __launch_bounds__(256)
void gemm_mfma(const void* __restrict__ Av, const unsigned short* __restrict__ Bt,
               void* __restrict__ Cv, const float* __restrict__ bias,
               int K, int Hdiv, int lda, int ldc, long sA, long sB, long sC)
{
    const int z = blockIdx.z;
    const float*          Af = (const float*)Av          + (long)(z / Hdiv) * sA;
    const unsigned short* Ah = (const unsigned short*)Av + (long)(z / Hdiv) * sA;
    const unsigned short* Bz = Bt + (long)(z % Hdiv) * sB;
    void* Cz = OUT16 ? (void*)((unsigned short*)Cv + (long)z * sC)
                     : (void*)((float*)Cv + (long)z * sC);
    gemm_body<CONVA, OUT16>(Af, Ah, Bz, Cz, bias, K, lda, ldc,
                            blockIdx.y * 128, blockIdx.x * 128, threadIdx.x);
}

// Fused K/V/Q projection: one dispatch, z in [0,36): which = z/12, bh = z%12.
__global__ __launch_bounds__(256)
void qkv_proj(const float* __restrict__ Xk, const float* __restrict__ Xv,
              const float* __restrict__ Xq,
              const unsigned short* __restrict__ WTk, const unsigned short* __restrict__ WTv,
              const unsigned short* __restrict__ WTq,
              unsigned short* __restrict__ Kp, unsigned short* __restrict__ Vp,
              unsigned short* __restrict__ Qp)
{
    const int z = blockIdx.z;
    const int which = z / 12, bh = z % 12;
    const int b = bh / H_, h = bh % H_;
    const float* X = (which == 0) ? Xk : (which == 1) ? Xv : Xq;
    const unsigned short* W = (which == 0) ? WTk : (which == 1) ? WTv : WTq;
    unsigned short* P = (which == 0) ? Kp : (which == 1) ? Vp : Qp;
    const float* Af = X + (long)b * T_ * E_;
    const unsigned short* Bz = W + (long)h * D_ * E_;
    unsigned short* Cz = P + (long)bh * T_ * D_;
    gemm_body<true, true>(Af, nullptr, Bz, Cz, nullptr, E_, E_, D_,
                          blockIdx.y * 128, blockIdx.x * 128, threadIdx.x);
}

// ---------------------------------------------------------------------------
// Split-K streaming MFMA causal flash attention.
// Block = 256 threads = 4 waves, ALL on the same (bh, 16-row q-tile);
// wave w handles k-tiles kt = w, w+4, w+8, ... (independent, barrier-free).
// K [bh][T][D] and Vt [bh][D][T] frags streamed from global (L2-resident).
// QK^T is c-outer: 4 independent accumulators per k-slice -> 4-way MFMA ILP.
// Epilogue: merge 4 partial (o,m,l) via LDS (alpha-scaled sum, 4 d-chunks).
// Grid 1536 XCD-chunked; heavy/light q-tiles interleaved per chunk.
// mfma_f32_16x16x32_f16: A row=lane&15,k=(lane>>4)*8+e; B col=lane&15,same k;
// C/D col=lane&15, row=(lane>>4)*4+reg.
// ---------------------------------------------------------------------------
__global__ __launch_bounds__(256, 3)
void flash_split(const unsigned short* __restrict__ Qb, const unsigned short* __restrict__ Kb,
                 const unsigned short* __restrict__ Vtb, unsigned short* __restrict__ Z2h,
                 float scale_log2e)
{
    __shared__ unsigned short Ps[4][16 * 72];
    __shared__ float Osh[4][16][68];      // +4 pad: merge reads 2-way max
    __shared__ float Msh[4][16], Lsh[4][16];

    const int p  = blockIdx.x;
    const int l  = (p & 7) * 192 + (p >> 3);      // XCD chunking (1536 = 8*192)
    const int bh = l >> 7;
    const int j  = l & 127;
    const int qt = (j & 1) ? (127 - (j >> 1)) : (j >> 1);   // heavy/light interleave
    const int b = bh / H_, h = bh % H_;
    const int tid = threadIdx.x;
    const int w = tid >> 6, lane = tid & 63;
    const int g = lane >> 4, fr = lane & 15;

    // Q fragments (rows qt*16..+15), pre-scaled into exp2 domain
    const unsigned short* qrow = Qb + ((long)bh * T_ + qt * 16 + fr) * D_;
    const _Float16 hs = (_Float16)scale_log2e;
    half8 qf[8];
    #pragma unroll
    for (int c = 0; c < 8; ++c) {
        qf[c] = *(const half8*)(qrow + c * 32 + g * 8);
        qf[c] *= hs;
    }

    f32x4 o[16];
    #pragma unroll
    for (int dt = 0; dt < 16; ++dt) o[dt] = (f32x4)(0.f);
    float mrow[4] = {-INFINITY, -INFINITY, -INFINITY, -INFINITY};
    float lrow[4] = {0.f, 0.f, 0.f, 0.f};

    const unsigned short* kbase = Kb  + (long)bh * T_ * D_;
    const unsigned short* vbase = Vtb + (long)bh * D_ * T_;
    const int nkt = (qt >> 2) + 1;
    const int rel = (qt & 3) * 16;

    for (int kt = w; kt < nkt; kt += 4) {
        const int k0 = kt * 64;

        // ---- QK^T: S[16q x 64k]; c-outer -> 4 independent acc chains ----
        f32x4 s[4];
        #pragma unroll
        for (int nt = 0; nt < 4; ++nt) s[nt] = (f32x4)(0.f);
        const unsigned short* kp = kbase + (long)k0 * D_ + g * 8;
        __builtin_amdgcn_s_setprio(1);
        #pragma unroll
        for (int c = 0; c < 8; ++c) {
            const unsigned short* kc = kp + c * 32;
            half8 kf0 = *(const half8*)(kc + (long)(fr) * D_);
            half8 kf1 = *(const half8*)(kc + (long)(16 + fr) * D_);
            half8 kf2 = *(const half8*)(kc + (long)(32 + fr) * D_);
            half8 kf3 = *(const half8*)(kc + (long)(48 + fr) * D_);
            s[0] = __builtin_amdgcn_mfma_f32_16x16x32_f16(qf[c], kf0, s[0], 0, 0, 0);
            s[1] = __builtin_amdgcn_mfma_f32_16x16x32_f16(qf[c], kf1, s[1], 0, 0, 0);
            s[2] = __builtin_amdgcn_mfma_f32_16x16x32_f16(qf[c], kf2, s[2], 0, 0, 0);
            s[3] = __builtin_amdgcn_mfma_f32_16x16x32_f16(qf[c], kf3, s[3], 0, 0, 0);
        }
        __builtin_amdgcn_s_setprio(0);

        // ---- causal mask (last tile only); values in log2 domain ----
        const bool diag = (kt == nkt - 1);
        float sv[4][4];
        #pragma unroll
        for (int nt = 0; nt < 4; ++nt)
            #pragma unroll
            for (int reg = 0; reg < 4; ++reg) {
                float v = s[nt][reg];
                if (diag && (nt * 16 + fr > rel + g * 4 + reg)) v = -INFINITY;
                sv[nt][reg] = v;
            }

        // ---- online softmax (rows on 16-lane groups), exp2 domain ----
        float alpha[4], psum[4];
        #pragma unroll
        for (int reg = 0; reg < 4; ++reg) {
            float tm = fmaxf(fmaxf(sv[0][reg], sv[1][reg]), fmaxf(sv[2][reg], sv[3][reg]));
            tm = fmaxf(tm, __shfl_xor(tm, 1));
            tm = fmaxf(tm, __shfl_xor(tm, 2));
            tm = fmaxf(tm, __shfl_xor(tm, 4));
            tm = fmaxf(tm, __shfl_xor(tm, 8));
            const float mnew = fmaxf(mrow[reg], tm);
            alpha[reg] = exp2f(mrow[reg] - mnew);
            mrow[reg] = mnew;
            psum[reg] = 0.f;
        }
        #pragma unroll
        for (int nt = 0; nt < 4; ++nt)
            #pragma unroll
            for (int reg = 0; reg < 4; ++reg) {
                const float pp = exp2f(sv[nt][reg] - mrow[reg]);
                psum[reg] += pp;
                Ps[w][(g * 4 + reg) * 72 + nt * 16 + fr] = f2h(pp);
            }
        #pragma unroll
        for (int reg = 0; reg < 4; ++reg) {
            float ps = psum[reg];
            ps += __shfl_xor(ps, 1);
            ps += __shfl_xor(ps, 2);
            ps += __shfl_xor(ps, 4);
            ps += __shfl_xor(ps, 8);
            lrow[reg] = lrow[reg] * alpha[reg] + ps;
        }
        #pragma unroll
        for (int dt = 0; dt < 16; ++dt)
            #pragma unroll
            for (int reg = 0; reg < 4; ++reg) o[dt][reg] *= alpha[reg];

        // ---- P back as A-frags (wave-private LDS; compiler orders ds ops) ----
        const half8 pf0 = *(const half8*)&Ps[w][fr * 72 + g * 8];
        const half8 pf1 = *(const half8*)&Ps[w][fr * 72 + 32 + g * 8];

        // ---- PV: O += P * V; 16 independent acc chains ----
        const unsigned short* vp = vbase + k0 + g * 8;
        __builtin_amdgcn_s_setprio(1);
        #pragma unroll
        for (int dt = 0; dt < 16; ++dt) {
            const unsigned short* vr = vp + (long)(dt * 16 + fr) * T_;
            o[dt] = __builtin_amdgcn_mfma_f32_16x16x32_f16(pf0, *(const half8*)vr, o[dt], 0, 0, 0);
            o[dt] = __builtin_amdgcn_mfma_f32_16x16x32_f16(pf1, *(const half8*)(vr + 32), o[dt], 0, 0, 0);
        }
        __builtin_amdgcn_s_setprio(0);
    }

    // ================= split-K merge across the 4 waves =================
    if (fr == 0) {
        #pragma unroll
        for (int reg = 0; reg < 4; ++reg) {
            Msh[w][g * 4 + reg] = mrow[reg];
            Lsh[w][g * 4 + reg] = lrow[reg];
        }
    }
    __syncthreads();

    // own rescale factor vs global max (per row g*4+reg)
    float aw[4];
    #pragma unroll
    for (int reg = 0; reg < 4; ++reg) {
        const int row = g * 4 + reg;
        float mst = fmaxf(fmaxf(Msh[0][row], Msh[1][row]), fmaxf(Msh[2][row], Msh[3][row]));
        aw[reg] = exp2f(mrow[reg] - mst);     // exp2(-inf)=0 for idle waves
    }

    // summing-thread mapping: row = tid>>4, cols scol..scol+3
    const int srow = tid >> 4;
    const int scol = (tid & 15) * 4;
    float msr = fmaxf(fmaxf(Msh[0][srow], Msh[1][srow]), fmaxf(Msh[2][srow], Msh[3][srow]));
    float lsr = Lsh[0][srow] * exp2f(Msh[0][srow] - msr)
              + Lsh[1][srow] * exp2f(Msh[1][srow] - msr)
              + Lsh[2][srow] * exp2f(Msh[2][srow] - msr)
              + Lsh[3][srow] * exp2f(Msh[3][srow] - msr);
    const float invl = 1.0f / lsr;

    #pragma unroll
    for (int c = 0; c < 4; ++c) {
        #pragma unroll
        for (int q = 0; q < 4; ++q)
            #pragma unroll
            for (int reg = 0; reg < 4; ++reg)
                Osh[w][g * 4 + reg][q * 16 + fr] = o[c * 4 + q][reg] * aw[reg];
        __syncthreads();

        ushort4v pk;
        #pragma unroll
        for (int e = 0; e < 4; ++e) {
            const float sum = Osh[0][srow][scol + e] + Osh[1][srow][scol + e]
                            + Osh[2][srow][scol + e] + Osh[3][srow][scol + e];
            pk[e] = f2h(sum * invl);
        }
        *(ushort4v*)(Z2h + ((long)b * T_ + qt * 16 + srow) * E_ + h * D_ + c * 64 + scol) = pk;
        __syncthreads();
    }
}

// ---------------------------------------------------------------------------
// d_in: keys, values, queries, Wk, Wq, Wv, Wo, bo (fp32)
// ws (f16): Kp|Vp|Qp|Vt (4 x 12.6MB) | Z2h 12.6MB | WTk|WTq|WTv|WoT 4.7MB
// ---------------------------------------------------------------------------
extern "C" void kernel_launch(void* const* d_in, const int* in_sizes, int n_in,
                              void* d_out, int out_size, void* d_ws, size_t ws_size,
                              hipStream_t stream)
{
    const float* Xk = (const float*)d_in[0];
    const float* Xv = (const float*)d_in[1];
    const float* Xq = (const float*)d_in[2];
    const float* Wk = (const float*)d_in[3];
    const float* Wq = (const float*)d_in[4];
    const float* Wv = (const float*)d_in[5];
    const float* Wo = (const float*)d_in[6];
    const float* bo = (const float*)d_in[7];
    float* out = (float*)d_out;

    const size_t phd = (size_t)B_ * H_ * T_ * D_;   // 6,291,456
    const size_t wsz = (size_t)H_ * E_ * D_;        // 589,824
    unsigned short* Kp  = (unsigned short*)d_ws;
    unsigned short* Vp  = Kp + phd;
    unsigned short* Qp  = Vp + phd;
    unsigned short* Vt  = Qp + phd;
    unsigned short* Z2h = Vt + phd;
    unsigned short* WTk = Z2h + (size_t)B_ * T_ * E_;
    unsigned short* WTq = WTk + wsz;
    unsigned short* WTv = WTq + wsz;
    unsigned short* WoT = WTv + wsz;

    dim3 blk(256);

    // Weights -> f16, [N][K]
    dim3 gtw(D_ / 32, E_ / 32, H_);
    transpose_cast<<<gtw, blk, 0, stream>>>(Wk, WTk, E_, D_);
    transpose_cast<<<gtw, blk, 0, stream>>>(Wq, WTq, E_, D_);
    transpose_cast<<<gtw, blk, 0, stream>>>(Wv, WTv, E_, D_);
    dim3 gto(E_ / 32, E_ / 32, 1);
    transpose_cast<<<gto, blk, 0, stream>>>(Wo, WoT, E_, E_);

    // Fused K/V/Q projections: one dispatch, 1152 blocks
    dim3 gproj(D_ / 128, T_ / 128, 36);
    qkv_proj<<<gproj, blk, 0, stream>>>(Xk, Xv, Xq, WTk, WTv, WTq, Kp, Vp, Qp);

    // V -> Vt [B*H][D][T]
    dim3 gtv(D_ / 64, T_ / 64, B_ * H_);
    transpose16<<<gtv, blk, 0, stream>>>(Vp, Vt, T_, D_);

    // Split-K streaming MFMA causal flash attention -> Z2h f16 [B][T][H*D]
    dim3 gf(128 * B_ * H_);                       // 1536 blocks x 4 waves
    flash_split<<<gf, blk, 0, stream>>>(Qp, Kp, Vt, Z2h,
                                        0.022097086912079608f * LOG2E);

    // Output projection: f16 Z * f16 Wo + bo -> fp32 out
    dim3 gout(E_ / 128, (B_ * T_) / 128, 1);
    gemm_mfma<false, false><<<gout, blk, 0, stream>>>(Z2h, WoT, out, bo, E_, 1, E_, E_,
                                                      0L, 0L, 0L);
}

// Round 9
// 261.371 us; speedup vs baseline: 9.0411x; 1.4949x over previous
//
#include <hip/hip_runtime.h>
#include <hip/hip_bf16.h>
#include <math.h>

#define B_ 4
#define T_ 2048
#define E_ 768
#define H_ 3
#define D_ 256
#define LOG2E 1.4426950408889634f

typedef __attribute__((ext_vector_type(8))) _Float16 half8;
typedef __attribute__((ext_vector_type(8))) unsigned short ushort8;
typedef __attribute__((ext_vector_type(4))) float f32x4;

static __device__ inline unsigned short f2h(float x) {
    _Float16 h = (_Float16)x;
    return *reinterpret_cast<unsigned short*>(&h);
}

#define GLOAD_LDS(SRC, DST) \
    __builtin_amdgcn_global_load_lds( \
        (const __attribute__((address_space(1))) void*)(SRC), \
        (__attribute__((address_space(3))) void*)(DST), 16, 0, 0)

// ---------------------------------------------------------------------------
// Transpose + fp32->fp16 cast: in [z][R][C] fp32 -> out [z][C][R] fp16.
// ---------------------------------------------------------------------------
__global__ __launch_bounds__(256)
void transpose_cast(const float* __restrict__ in, unsigned short* __restrict__ out,
                    int R, int Ccols)
{
    __shared__ float tile[32][33];
    const long zoff = (long)blockIdx.z * R * Ccols;
    const int c0 = blockIdx.x * 32;
    const int r0 = blockIdx.y * 32;
    const int t  = threadIdx.x;
    const int cc = t & 31, rr = t >> 5;
    #pragma unroll
    for (int i = 0; i < 4; ++i)
        tile[rr + i * 8][cc] = in[zoff + (long)(r0 + rr + i * 8) * Ccols + c0 + cc];
    __syncthreads();
    const int rr2 = t & 31, cc2 = t >> 5;
    #pragma unroll
    for (int i = 0; i < 4; ++i)
        out[zoff + (long)(c0 + cc2 + i * 8) * R + r0 + rr2] = f2h(tile[rr2][cc2 + i * 8]);
}

// ---------------------------------------------------------------------------
// fp16 transpose: in [z][R][C] f16 -> out [z][C][R] f16. 64x64 tiles,
// XOR-swizzled LDS (conflict-free both phases). (Validated R6-R8.)
// ---------------------------------------------------------------------------
__global__ __launch_bounds__(256)
void transpose16(const unsigned short* __restrict__ in, unsigned short* __restrict__ out,
                 int R, int Ccols)
{
    __shared__ unsigned short tile[64 * 64];
    char* tb = (char*)tile;
    const long zoff = (long)blockIdx.z * R * Ccols;
    const int r0 = blockIdx.y * 64, c0 = blockIdx.x * 64;
    const int t = threadIdx.x;
    #pragma unroll
    for (int i = 0; i < 2; ++i) {
        const int rr = (t >> 3) + i * 32;
        const int gc = (t & 7) * 8;
        ushort8 v = *(const ushort8*)(in + zoff + (long)(r0 + rr) * Ccols + c0 + gc);
        *(ushort8*)(tb + rr * 128 + ((gc * 2) ^ (((rr >> 3) & 7) << 4))) = v;
    }
    __syncthreads();
    #pragma unroll
    for (int i = 0; i < 2; ++i) {
        const int cc = (t >> 3) + i * 32;
        const int gr = (t & 7) * 8;
        ushort8 v;
        #pragma unroll
        for (int e = 0; e < 8; ++e) {
            const int row = gr + e;
            v[e] = *(const unsigned short*)(tb + row * 128 + ((cc * 2) ^ (((row >> 3) & 7) << 4)));
        }
        *(ushort8*)(out + zoff + (long)(c0 + cc) * R + r0 + gr) = v;
    }
}

// ---------------------------------------------------------------------------
// fp16 MFMA GEMM body (validated R6-R8): C = A * B^T on one z-slice.
// ---------------------------------------------------------------------------
template<bool CONVA, bool OUT16>
__device__ __forceinline__
void gemm_body(const float* Af, const unsigned short* Ah, const unsigned short* Bz,
               void* Cz, const float* bias, int K, int lda, int ldc,
               int m0, int n0, int tid)
{
    __shared__ unsigned short As[128 * 32];
    __shared__ unsigned short Bs[128 * 32];

    const int lane = tid & 63, wid = tid >> 6;
    const int wm = wid >> 1, wn = wid & 1;
    const int fr = lane & 15, fg = lane >> 4;

    f32x4 acc[4][4];
    #pragma unroll
    for (int mt = 0; mt < 4; ++mt)
        #pragma unroll
        for (int nt = 0; nt < 4; ++nt) acc[mt][nt] = (f32x4)(0.f);

    for (int k0 = 0; k0 < K; k0 += 32) {
        #pragma unroll
        for (int i = 0; i < 2; ++i) {
            const int G = tid + i * 256;
            const int row = G >> 2, g = G & 3;
            ushort8 pa;
            if (CONVA) {
                const float* s = Af + (long)(m0 + row) * lda + k0 + g * 8;
                float4 f0 = *(const float4*)s, f1 = *(const float4*)(s + 4);
                pa[0] = f2h(f0.x); pa[1] = f2h(f0.y); pa[2] = f2h(f0.z); pa[3] = f2h(f0.w);
                pa[4] = f2h(f1.x); pa[5] = f2h(f1.y); pa[6] = f2h(f1.z); pa[7] = f2h(f1.w);
            } else {
                pa = *(const ushort8*)(Ah + (long)(m0 + row) * lda + k0 + g * 8);
            }
            *(ushort8*)&As[row * 32 + g * 8] = pa;
            *(ushort8*)&Bs[row * 32 + g * 8] =
                *(const ushort8*)(Bz + (long)(n0 + row) * K + k0 + g * 8);
        }
        __syncthreads();

        half8 a[4], b[4];
        #pragma unroll
        for (int mt = 0; mt < 4; ++mt)
            a[mt] = *(const half8*)&As[(wm * 64 + mt * 16 + fr) * 32 + fg * 8];
        #pragma unroll
        for (int nt = 0; nt < 4; ++nt)
            b[nt] = *(const half8*)&Bs[(wn * 64 + nt * 16 + fr) * 32 + fg * 8];
        #pragma unroll
        for (int mt = 0; mt < 4; ++mt)
            #pragma unroll
            for (int nt = 0; nt < 4; ++nt)
                acc[mt][nt] = __builtin_amdgcn_mfma_f32_16x16x32_f16(
                                  a[mt], b[nt], acc[mt][nt], 0, 0, 0);
        __syncthreads();
    }

    #pragma unroll
    for (int nt = 0; nt < 4; ++nt) {
        const int col = n0 + wn * 64 + nt * 16 + fr;
        const float badd = bias ? bias[col] : 0.f;
        #pragma unroll
        for (int mt = 0; mt < 4; ++mt) {
            const int row = m0 + wm * 64 + mt * 16 + fg * 4;
            #pragma unroll
            for (int reg = 0; reg < 4; ++reg) {
                if (OUT16)
                    ((unsigned short*)Cz)[(long)(row + reg) * ldc + col] =
                        f2h(acc[mt][nt][reg] + badd);
                else
                    ((float*)Cz)[(long)(row + reg) * ldc + col] =
                        acc[mt][nt][reg] + badd;
            }
        }
    }
}

template<bool CONVA, bool OUT16>
__global__ __launch_bounds__(256)
void gemm_mfma(const void* __restrict__ Av, const unsigned short* __restrict__ Bt,
               void* __restrict__ Cv, const float* __restrict__ bias,
               int K, int Hdiv, int lda, int ldc, long sA, long sB, long sC)
{
    const int z = blockIdx.z;
    const float*          Af = (const float*)Av          + (long)(z / Hdiv) * sA;
    const unsigned short* Ah = (const unsigned short*)Av + (long)(z / Hdiv) * sA;
    const unsigned short* Bz = Bt + (long)(z % Hdiv) * sB;
    void* Cz = OUT16 ? (void*)((unsigned short*)Cv + (long)z * sC)
                     : (void*)((float*)Cv + (long)z * sC);
    gemm_body<CONVA, OUT16>(Af, Ah, Bz, Cz, bias, K, lda, ldc,
                            blockIdx.y * 128, blockIdx.x * 128, threadIdx.x);
}

// Fused K/V/Q projection: one dispatch, z in [0,36): which = z/12, bh = z%12.
__global__ __launch_bounds__(256)
void qkv_proj(const float* __restrict__ Xk, const float* __restrict__ Xv,
              const float* __restrict__ Xq,
              const unsigned short* __restrict__ WTk, const unsigned short* __restrict__ WTv,
              const unsigned short* __restrict__ WTq,
              unsigned short* __restrict__ Kp, unsigned short* __restrict__ Vp,
              unsigned short* __restrict__ Qp)
{
    const int z = blockIdx.z;
    const int which = z / 12, bh = z % 12;
    const int b = bh / H_, h = bh % H_;
    const float* X = (which == 0) ? Xk : (which == 1) ? Xv : Xq;
    const unsigned short* W = (which == 0) ? WTk : (which == 1) ? WTv : WTq;
    unsigned short* P = (which == 0) ? Kp : (which == 1) ? Vp : Qp;
    const float* Af = X + (long)b * T_ * E_;
    const unsigned short* Bz = W + (long)h * D_ * E_;
    unsigned short* Cz = P + (long)bh * T_ * D_;
    gemm_body<true, true>(Af, nullptr, Bz, Cz, nullptr, E_, E_, D_,
                          blockIdx.y * 128, blockIdx.x * 128, threadIdx.x);
}

// ---------------------------------------------------------------------------
// LDS-staged double-buffered MFMA causal flash attention.
// Block = 64 q-rows, 4 waves (16 rows each), BK=32.
// K tile [32][256] and Vt tile [256][32] staged via global_load_lds with
// PRE-SWIZZLED GLOBAL SOURCE + linear LDS dest; reads apply the same XOR
// (rule #21): K granule ^= (krow&7); Vt granule ^= ((drow>>1)&3).
// Both read patterns land 8 bank-quads x 2 lanes = 2-way = free (m136).
// Double-buffer + counted vmcnt(8) prefetch (T3 2-phase, T4): stage tile
// t+1 before computing tile t; raw s_barrier (NOT __syncthreads) so the
// prefetch stays in flight across the barrier.
// Grid 384 = 32 qtiles x 12 bh, XCD-chunked, heavy q-tiles first.
// mfma_f32_16x16x32_f16: A row=lane&15,k=(lane>>4)*8+e; B col=lane&15,same k;
// C/D col=lane&15, row=(lane>>4)*4+reg.
// ---------------------------------------------------------------------------
__global__ __launch_bounds__(256, 2)
void flash_lds(const unsigned short* __restrict__ Qb, const unsigned short* __restrict__ Kb,
               const unsigned short* __restrict__ Vtb, unsigned short* __restrict__ Z2h,
               float scale_log2e)
{
    __shared__ unsigned short Ktile[2][32 * 256];   // 16KB each
    __shared__ unsigned short Vtile[2][256 * 32];   // 16KB each
    __shared__ unsigned short Ps[4][16 * 72];       // 9KB

    const int p  = blockIdx.x;
    const int l  = (p & 7) * 48 + (p >> 3);          // 384 = 8*48, bijective
    const int bh = l >> 5;
    const int j  = l & 31;
    const int qt = (j & 1) ? (j >> 1) : 31 - (j >> 1);   // heavy first
    const int b = bh / H_, h = bh % H_;
    const int tid = threadIdx.x;
    const int w = tid >> 6, lane = tid & 63;
    const int g = lane >> 4, fr = lane & 15;
    const int qw0 = qt * 64 + w * 16;                // wave's first q-row

    const unsigned short* kg = Kb  + (long)bh * T_ * D_;
    const unsigned short* vg = Vtb + (long)bh * D_ * T_;

    // Q fragments (rows qw0..+15), pre-scaled into exp2 domain
    const unsigned short* qrow = Qb + ((long)bh * T_ + qw0 + fr) * D_;
    const _Float16 hs = (_Float16)scale_log2e;
    half8 qf[8];
    #pragma unroll
    for (int c = 0; c < 8; ++c) {
        qf[c] = *(const half8*)(qrow + c * 32 + g * 8);
        qf[c] *= hs;
    }

    f32x4 o[16];
    #pragma unroll
    for (int dt = 0; dt < 16; ++dt) o[dt] = (f32x4)(0.f);
    float mrow[4] = {-INFINITY, -INFINITY, -INFINITY, -INFINITY};
    float lrow[4] = {0.f, 0.f, 0.f, 0.f};

    const int nkt = 2 * qt + 2;

    // cooperative stage of k-tile kt into buffer bufi (8 VMEM ops/thread)
    auto STAGE = [&](int bufi, int kt) {
        const int k0 = kt * 32;
        #pragma unroll
        for (int i = 0; i < 4; ++i) {                // K: 1024 granules of 16B
            const int L = tid + i * 256;
            const int r = L >> 5, cg = L & 31;
            GLOAD_LDS(kg + (long)(k0 + r) * D_ + ((cg ^ (r & 7)) * 8),
                      &Ktile[bufi][L * 8]);
        }
        #pragma unroll
        for (int i = 0; i < 4; ++i) {                // Vt: 1024 granules
            const int L = tid + i * 256;
            const int dr = L >> 2, gq = L & 3;
            GLOAD_LDS(vg + (long)dr * T_ + k0 + ((gq ^ ((dr >> 1) & 3)) * 8),
                      &Vtile[bufi][L * 8]);
        }
    };

    STAGE(0, 0);
    int buf = 0;
    for (int kt = 0; kt < nkt; ++kt) {
        const bool pf = (kt + 1 < nkt);
        if (pf) {
            STAGE(buf ^ 1, kt + 1);
            asm volatile("s_waitcnt vmcnt(8)" ::: "memory");   // current tile done
        } else {
            asm volatile("s_waitcnt vmcnt(0)" ::: "memory");
        }
        __builtin_amdgcn_sched_barrier(0);
        __builtin_amdgcn_s_barrier();
        __builtin_amdgcn_sched_barrier(0);

        const int k0 = kt * 32;
        if (k0 <= qw0 + 15) {                        // wave has live rows here
            // ---- QK^T: S[16q x 32k] ----
            f32x4 s[2];
            s[0] = (f32x4)(0.f); s[1] = (f32x4)(0.f);
            const int kkey = fr & 7;
            __builtin_amdgcn_s_setprio(1);
            #pragma unroll
            for (int c = 0; c < 8; ++c) {
                #pragma unroll
                for (int nt = 0; nt < 2; ++nt) {
                    const int kr = nt * 16 + fr;
                    half8 kf = *(const half8*)&Ktile[buf][(kr * 32 + ((c * 4 + g) ^ kkey)) * 8];
                    s[nt] = __builtin_amdgcn_mfma_f32_16x16x32_f16(qf[c], kf, s[nt], 0, 0, 0);
                }
            }
            __builtin_amdgcn_s_setprio(0);

            // ---- causal mask (log2 domain) ----
            const bool diag = (k0 + 31 > qw0);
            float sv[2][4];
            #pragma unroll
            for (int nt = 0; nt < 2; ++nt)
                #pragma unroll
                for (int reg = 0; reg < 4; ++reg) {
                    float v = s[nt][reg];
                    if (diag && (k0 + nt * 16 + fr > qw0 + g * 4 + reg)) v = -INFINITY;
                    sv[nt][reg] = v;
                }

            // ---- online softmax (rows on 16-lane groups) ----
            float alpha[4], psum[4];
            #pragma unroll
            for (int reg = 0; reg < 4; ++reg) {
                float tm = fmaxf(sv[0][reg], sv[1][reg]);
                tm = fmaxf(tm, __shfl_xor(tm, 1));
                tm = fmaxf(tm, __shfl_xor(tm, 2));
                tm = fmaxf(tm, __shfl_xor(tm, 4));
                tm = fmaxf(tm, __shfl_xor(tm, 8));
                const float mnew = fmaxf(mrow[reg], tm);
                alpha[reg] = exp2f(mrow[reg] - mnew);
                mrow[reg] = mnew;
                psum[reg] = 0.f;
            }
            #pragma unroll
            for (int nt = 0; nt < 2; ++nt)
                #pragma unroll
                for (int reg = 0; reg < 4; ++reg) {
                    const float pp = exp2f(sv[nt][reg] - mrow[reg]);
                    psum[reg] += pp;
                    Ps[w][(g * 4 + reg) * 72 + nt * 16 + fr] = f2h(pp);
                }
            #pragma unroll
            for (int reg = 0; reg < 4; ++reg) {
                float ps = psum[reg];
                ps += __shfl_xor(ps, 1);
                ps += __shfl_xor(ps, 2);
                ps += __shfl_xor(ps, 4);
                ps += __shfl_xor(ps, 8);
                lrow[reg] = lrow[reg] * alpha[reg] + ps;
            }
            #pragma unroll
            for (int dt = 0; dt < 16; ++dt)
                #pragma unroll
                for (int reg = 0; reg < 4; ++reg) o[dt][reg] *= alpha[reg];

            // ---- P as A-frag (k=0..31), wave-private LDS round-trip ----
            const half8 pf0 = *(const half8*)&Ps[w][fr * 72 + g * 8];

            // ---- PV: O[16q x 256d] += P * V ----
            const int vkey = g ^ ((fr >> 1) & 3);
            __builtin_amdgcn_s_setprio(1);
            #pragma unroll
            for (int dt = 0; dt < 16; ++dt) {
                const int dr = dt * 16 + fr;
                half8 vf = *(const half8*)&Vtile[buf][(dr * 4 + vkey) * 8];
                o[dt] = __builtin_amdgcn_mfma_f32_16x16x32_f16(pf0, vf, o[dt], 0, 0, 0);
            }
            __builtin_amdgcn_s_setprio(0);
        }
        __builtin_amdgcn_sched_barrier(0);
        __builtin_amdgcn_s_barrier();                // all waves done reading buf
        buf ^= 1;
    }

    // ---- epilogue: O /= l, write f16 into [B][T][H*D] ----
    float inv[4];
    #pragma unroll
    for (int reg = 0; reg < 4; ++reg) inv[reg] = 1.f / lrow[reg];
    const long rowbase = ((long)b * T_ + qw0 + g * 4) * E_ + h * D_;
    #pragma unroll
    for (int reg = 0; reg < 4; ++reg) {
        unsigned short* dst = Z2h + rowbase + (long)reg * E_ + fr;
        #pragma unroll
        for (int dt = 0; dt < 16; ++dt)
            dst[dt * 16] = f2h(o[dt][reg] * inv[reg]);
    }
}

// ---------------------------------------------------------------------------
// d_in: keys, values, queries, Wk, Wq, Wv, Wo, bo (fp32)
// ws (f16): Kp|Vp|Qp|Vt (4 x 12.6MB) | Z2h 12.6MB | WTk|WTq|WTv|WoT 4.7MB
// ---------------------------------------------------------------------------
extern "C" void kernel_launch(void* const* d_in, const int* in_sizes, int n_in,
                              void* d_out, int out_size, void* d_ws, size_t ws_size,
                              hipStream_t stream)
{
    const float* Xk = (const float*)d_in[0];
    const float* Xv = (const float*)d_in[1];
    const float* Xq = (const float*)d_in[2];
    const float* Wk = (const float*)d_in[3];
    const float* Wq = (const float*)d_in[4];
    const float* Wv = (const float*)d_in[5];
    const float* Wo = (const float*)d_in[6];
    const float* bo = (const float*)d_in[7];
    float* out = (float*)d_out;

    const size_t phd = (size_t)B_ * H_ * T_ * D_;   // 6,291,456
    const size_t wsz = (size_t)H_ * E_ * D_;        // 589,824
    unsigned short* Kp  = (unsigned short*)d_ws;
    unsigned short* Vp  = Kp + phd;
    unsigned short* Qp  = Vp + phd;
    unsigned short* Vt  = Qp + phd;
    unsigned short* Z2h = Vt + phd;
    unsigned short* WTk = Z2h + (size_t)B_ * T_ * E_;
    unsigned short* WTq = WTk + wsz;
    unsigned short* WTv = WTq + wsz;
    unsigned short* WoT = WTv + wsz;

    dim3 blk(256);

    // Weights -> f16, [N][K]
    dim3 gtw(D_ / 32, E_ / 32, H_);
    transpose_cast<<<gtw, blk, 0, stream>>>(Wk, WTk, E_, D_);
    transpose_cast<<<gtw, blk, 0, stream>>>(Wq, WTq, E_, D_);
    transpose_cast<<<gtw, blk, 0, stream>>>(Wv, WTv, E_, D_);
    dim3 gto(E_ / 32, E_ / 32, 1);
    transpose_cast<<<gto, blk, 0, stream>>>(Wo, WoT, E_, E_);

    // Fused K/V/Q projections: one dispatch, 1152 blocks
    dim3 gproj(D_ / 128, T_ / 128, 36);
    qkv_proj<<<gproj, blk, 0, stream>>>(Xk, Xv, Xq, WTk, WTv, WTq, Kp, Vp, Qp);

    // V -> Vt [B*H][D][T]
    dim3 gtv(D_ / 64, T_ / 64, B_ * H_);
    transpose16<<<gtv, blk, 0, stream>>>(Vp, Vt, T_, D_);

    // LDS-staged double-buffered MFMA flash attention -> Z2h f16 [B][T][H*D]
    dim3 gf(32 * B_ * H_);                          // 384 blocks x 4 waves
    flash_lds<<<gf, blk, 0, stream>>>(Qp, Kp, Vt, Z2h,
                                      0.022097086912079608f * LOG2E);

    // Output projection: f16 Z * f16 Wo + bo -> fp32 out
    dim3 gout(E_ / 128, (B_ * T_) / 128, 1);
    gemm_mfma<false, false><<<gout, blk, 0, stream>>>(Z2h, WoT, out, bo, E_, 1, E_, E_,
                                                      0L, 0L, 0L);
}

// Round 10
// 231.613 us; speedup vs baseline: 10.2027x; 1.1285x over previous
//
#include <hip/hip_runtime.h>
#include <hip/hip_bf16.h>
#include <math.h>

#define B_ 4
#define T_ 2048
#define E_ 768
#define H_ 3
#define D_ 256
#define LOG2E 1.4426950408889634f

typedef __attribute__((ext_vector_type(8))) _Float16 half8;
typedef __attribute__((ext_vector_type(8))) unsigned short ushort8;
typedef __attribute__((ext_vector_type(4))) float f32x4;

static __device__ inline unsigned short f2h(float x) {
    _Float16 h = (_Float16)x;
    return *reinterpret_cast<unsigned short*>(&h);
}

#define GLOAD_LDS(SRC, DST) \
    __builtin_amdgcn_global_load_lds( \
        (const __attribute__((address_space(1))) void*)(SRC), \
        (__attribute__((address_space(3))) void*)(DST), 16, 0, 0)

// ---------------------------------------------------------------------------
// All weight transposes in ONE dispatch: z<9 -> head-slice hd=z%3 of
// {Wk,Wq,Wv}[z/3] ([E][D] -> [D][E] f16); z==9 -> Wo ([E][E] -> [E][E] f16).
// ---------------------------------------------------------------------------
__global__ __launch_bounds__(256)
void transpose_cast_all(const float* __restrict__ Wk, const float* __restrict__ Wq,
                        const float* __restrict__ Wv, const float* __restrict__ Wo,
                        unsigned short* __restrict__ WTk, unsigned short* __restrict__ WTq,
                        unsigned short* __restrict__ WTv, unsigned short* __restrict__ WoT)
{
    __shared__ float tile[32][33];
    const int z = blockIdx.z;
    const float* in; unsigned short* out; int R, C;
    if (z < 9) {
        const int mat = z / 3, hd = z % 3;
        R = E_; C = D_;
        in  = (mat == 0 ? Wk  : mat == 1 ? Wq  : Wv)  + (long)hd * E_ * D_;
        out = (mat == 0 ? WTk : mat == 1 ? WTq : WTv) + (long)hd * D_ * E_;
    } else {
        R = E_; C = E_;
        in = Wo; out = WoT;
    }
    const int c0 = blockIdx.x * 32;
    const int r0 = blockIdx.y * 32;
    if (c0 >= C) return;
    const int t  = threadIdx.x;
    const int cc = t & 31, rr = t >> 5;
    #pragma unroll
    for (int i = 0; i < 4; ++i)
        tile[rr + i * 8][cc] = in[(long)(r0 + rr + i * 8) * C + c0 + cc];
    __syncthreads();
    const int rr2 = t & 31, cc2 = t >> 5;
    #pragma unroll
    for (int i = 0; i < 4; ++i)
        out[(long)(c0 + cc2 + i * 8) * R + r0 + rr2] = f2h(tile[rr2][cc2 + i * 8]);
}

// ---------------------------------------------------------------------------
// fp16 transpose: in [z][R][C] f16 -> out [z][C][R] f16. 64x64 tiles,
// XOR-swizzled LDS (conflict-free both phases). (Validated R6-R9.)
// ---------------------------------------------------------------------------
__global__ __launch_bounds__(256)
void transpose16(const unsigned short* __restrict__ in, unsigned short* __restrict__ out,
                 int R, int Ccols)
{
    __shared__ unsigned short tile[64 * 64];
    char* tb = (char*)tile;
    const long zoff = (long)blockIdx.z * R * Ccols;
    const int r0 = blockIdx.y * 64, c0 = blockIdx.x * 64;
    const int t = threadIdx.x;
    #pragma unroll
    for (int i = 0; i < 2; ++i) {
        const int rr = (t >> 3) + i * 32;
        const int gc = (t & 7) * 8;
        ushort8 v = *(const ushort8*)(in + zoff + (long)(r0 + rr) * Ccols + c0 + gc);
        *(ushort8*)(tb + rr * 128 + ((gc * 2) ^ (((rr >> 3) & 7) << 4))) = v;
    }
    __syncthreads();
    #pragma unroll
    for (int i = 0; i < 2; ++i) {
        const int cc = (t >> 3) + i * 32;
        const int gr = (t & 7) * 8;
        ushort8 v;
        #pragma unroll
        for (int e = 0; e < 8; ++e) {
            const int row = gr + e;
            v[e] = *(const unsigned short*)(tb + row * 128 + ((cc * 2) ^ (((row >> 3) & 7) << 4)));
        }
        *(ushort8*)(out + zoff + (long)(c0 + cc) * R + r0 + gr) = v;
    }
}

// ---------------------------------------------------------------------------
// fp16 MFMA GEMM body (validated R6-R9): C = A * B^T on one z-slice.
// ---------------------------------------------------------------------------
template<bool CONVA, bool OUT16>
__device__ __forceinline__
void gemm_body(const float* Af, const unsigned short* Ah, const unsigned short* Bz,
               void* Cz, const float* bias, int K, int lda, int ldc,
               int m0, int n0, int tid)
{
    __shared__ unsigned short As[128 * 32];
    __shared__ unsigned short Bs[128 * 32];

    const int lane = tid & 63, wid = tid >> 6;
    const int wm = wid >> 1, wn = wid & 1;
    const int fr = lane & 15, fg = lane >> 4;

    f32x4 acc[4][4];
    #pragma unroll
    for (int mt = 0; mt < 4; ++mt)
        #pragma unroll
        for (int nt = 0; nt < 4; ++nt) acc[mt][nt] = (f32x4)(0.f);

    for (int k0 = 0; k0 < K; k0 += 32) {
        #pragma unroll
        for (int i = 0; i < 2; ++i) {
            const int G = tid + i * 256;
            const int row = G >> 2, g = G & 3;
            ushort8 pa;
            if (CONVA) {
                const float* s = Af + (long)(m0 + row) * lda + k0 + g * 8;
                float4 f0 = *(const float4*)s, f1 = *(const float4*)(s + 4);
                pa[0] = f2h(f0.x); pa[1] = f2h(f0.y); pa[2] = f2h(f0.z); pa[3] = f2h(f0.w);
                pa[4] = f2h(f1.x); pa[5] = f2h(f1.y); pa[6] = f2h(f1.z); pa[7] = f2h(f1.w);
            } else {
                pa = *(const ushort8*)(Ah + (long)(m0 + row) * lda + k0 + g * 8);
            }
            *(ushort8*)&As[row * 32 + g * 8] = pa;
            *(ushort8*)&Bs[row * 32 + g * 8] =
                *(const ushort8*)(Bz + (long)(n0 + row) * K + k0 + g * 8);
        }
        __syncthreads();

        half8 a[4], b[4];
        #pragma unroll
        for (int mt = 0; mt < 4; ++mt)
            a[mt] = *(const half8*)&As[(wm * 64 + mt * 16 + fr) * 32 + fg * 8];
        #pragma unroll
        for (int nt = 0; nt < 4; ++nt)
            b[nt] = *(const half8*)&Bs[(wn * 64 + nt * 16 + fr) * 32 + fg * 8];
        #pragma unroll
        for (int mt = 0; mt < 4; ++mt)
            #pragma unroll
            for (int nt = 0; nt < 4; ++nt)
                acc[mt][nt] = __builtin_amdgcn_mfma_f32_16x16x32_f16(
                                  a[mt], b[nt], acc[mt][nt], 0, 0, 0);
        __syncthreads();
    }

    #pragma unroll
    for (int nt = 0; nt < 4; ++nt) {
        const int col = n0 + wn * 64 + nt * 16 + fr;
        const float badd = bias ? bias[col] : 0.f;
        #pragma unroll
        for (int mt = 0; mt < 4; ++mt) {
            const int row = m0 + wm * 64 + mt * 16 + fg * 4;
            #pragma unroll
            for (int reg = 0; reg < 4; ++reg) {
                if (OUT16)
                    ((unsigned short*)Cz)[(long)(row + reg) * ldc + col] =
                        f2h(acc[mt][nt][reg] + badd);
                else
                    ((float*)Cz)[(long)(row + reg) * ldc + col] =
                        acc[mt][nt][reg] + badd;
            }
        }
    }
}

template<bool CONVA, bool OUT16>
__global__ __launch_bounds__(256)
void gemm_mfma(const void* __restrict__ Av, const unsigned short* __restrict__ Bt,
               void* __restrict__ Cv, const float* __restrict__ bias,
               int K, int Hdiv, int lda, int ldc, long sA, long sB, long sC)
{
    const int z = blockIdx.z;
    const float*          Af = (const float*)Av          + (long)(z / Hdiv) * sA;
    const unsigned short* Ah = (const unsigned short*)Av + (long)(z / Hdiv) * sA;
    const unsigned short* Bz = Bt + (long)(z % Hdiv) * sB;
    void* Cz = OUT16 ? (void*)((unsigned short*)Cv + (long)z * sC)
                     : (void*)((float*)Cv + (long)z * sC);
    gemm_body<CONVA, OUT16>(Af, Ah, Bz, Cz, bias, K, lda, ldc,
                            blockIdx.y * 128, blockIdx.x * 128, threadIdx.x);
}

// Fused K/V/Q projection: one dispatch, z in [0,36): which = z/12, bh = z%12.
__global__ __launch_bounds__(256)
void qkv_proj(const float* __restrict__ Xk, const float* __restrict__ Xv,
              const float* __restrict__ Xq,
              const unsigned short* __restrict__ WTk, const unsigned short* __restrict__ WTv,
              const unsigned short* __restrict__ WTq,
              unsigned short* __restrict__ Kp, unsigned short* __restrict__ Vp,
              unsigned short* __restrict__ Qp)
{
    const int z = blockIdx.z;
    const int which = z / 12, bh = z % 12;
    const int b = bh / H_, h = bh % H_;
    const float* X = (which == 0) ? Xk : (which == 1) ? Xv : Xq;
    const unsigned short* W = (which == 0) ? WTk : (which == 1) ? WTv : WTq;
    unsigned short* P = (which == 0) ? Kp : (which == 1) ? Vp : Qp;
    const float* Af = X + (long)b * T_ * E_;
    const unsigned short* Bz = W + (long)h * D_ * E_;
    unsigned short* Cz = P + (long)bh * T_ * D_;
    gemm_body<true, true>(Af, nullptr, Bz, Cz, nullptr, E_, E_, D_,
                          blockIdx.y * 128, blockIdx.x * 128, threadIdx.x);
}

// ---------------------------------------------------------------------------
// LDS-staged double-buffered MFMA causal flash attention, WAVE-PAIRED for
// uniform block work: block p -> (bh = p%12, pi = p/12); waves 0,1 own the
// 32-row q-tile qtA=pi, waves 2,3 own qtB=63-pi. Active wave-iters per block
// = 2(pi+1) + 2(64-pi) = 130, IDENTICAL for all 384 blocks -> no CU-level
// load imbalance (R9's limiter: triangular blocks, worst CU ~2.6x average).
// Staging/vmcnt/softmax machinery unchanged from validated R9.
// ---------------------------------------------------------------------------
__global__ __launch_bounds__(256, 2)
void flash_lds(const unsigned short* __restrict__ Qb, const unsigned short* __restrict__ Kb,
               const unsigned short* __restrict__ Vtb, unsigned short* __restrict__ Z2h,
               float scale_log2e)
{
    __shared__ unsigned short Ktile[2][32 * 256];   // 16KB each
    __shared__ unsigned short Vtile[2][256 * 32];   // 16KB each
    __shared__ unsigned short Ps[4][16 * 72];       // 9KB

    const int p  = blockIdx.x;
    const int bh = p % 12;
    const int pi = p / 12;                     // 0..31
    const int qtB = 63 - pi;                   // 32-row tile indices
    const int b = bh / H_, h = bh % H_;
    const int tid = threadIdx.x;
    const int w = tid >> 6, lane = tid & 63;
    const int g = lane >> 4, fr = lane & 15;
    // wave's first q-row: waves 0,1 -> tile qtA=pi; waves 2,3 -> tile qtB
    const int qw0 = (w < 2) ? (pi * 32 + w * 16) : (qtB * 32 + (w - 2) * 16);

    const unsigned short* kg = Kb  + (long)bh * T_ * D_;
    const unsigned short* vg = Vtb + (long)bh * D_ * T_;

    // Q fragments (rows qw0..+15), pre-scaled into exp2 domain
    const unsigned short* qrow = Qb + ((long)bh * T_ + qw0 + fr) * D_;
    const _Float16 hs = (_Float16)scale_log2e;
    half8 qf[8];
    #pragma unroll
    for (int c = 0; c < 8; ++c) {
        qf[c] = *(const half8*)(qrow + c * 32 + g * 8);
        qf[c] *= hs;
    }

    f32x4 o[16];
    #pragma unroll
    for (int dt = 0; dt < 16; ++dt) o[dt] = (f32x4)(0.f);
    float mrow[4] = {-INFINITY, -INFINITY, -INFINITY, -INFINITY};
    float lrow[4] = {0.f, 0.f, 0.f, 0.f};

    const int nkt = qtB + 1;                   // k-tiles of 32 (covers both tiles)

    // cooperative stage of k-tile kt into buffer bufi (8 VMEM ops/thread)
    auto STAGE = [&](int bufi, int kt) {
        const int k0 = kt * 32;
        #pragma unroll
        for (int i = 0; i < 4; ++i) {                // K: 1024 granules of 16B
            const int L = tid + i * 256;
            const int r = L >> 5, cg = L & 31;
            GLOAD_LDS(kg + (long)(k0 + r) * D_ + ((cg ^ (r & 7)) * 8),
                      &Ktile[bufi][L * 8]);
        }
        #pragma unroll
        for (int i = 0; i < 4; ++i) {                // Vt: 1024 granules
            const int L = tid + i * 256;
            const int dr = L >> 2, gq = L & 3;
            GLOAD_LDS(vg + (long)dr * T_ + k0 + ((gq ^ ((dr >> 1) & 3)) * 8),
                      &Vtile[bufi][L * 8]);
        }
    };

    STAGE(0, 0);
    int buf = 0;
    for (int kt = 0; kt < nkt; ++kt) {
        const bool pf = (kt + 1 < nkt);
        if (pf) {
            STAGE(buf ^ 1, kt + 1);
            asm volatile("s_waitcnt vmcnt(8)" ::: "memory");   // current tile done
        } else {
            asm volatile("s_waitcnt vmcnt(0)" ::: "memory");
        }
        __builtin_amdgcn_sched_barrier(0);
        __builtin_amdgcn_s_barrier();
        __builtin_amdgcn_sched_barrier(0);

        const int k0 = kt * 32;
        if (k0 <= qw0 + 15) {                        // wave has live rows here
            // ---- QK^T: S[16q x 32k] ----
            f32x4 s[2];
            s[0] = (f32x4)(0.f); s[1] = (f32x4)(0.f);
            const int kkey = fr & 7;
            __builtin_amdgcn_s_setprio(1);
            #pragma unroll
            for (int c = 0; c < 8; ++c) {
                #pragma unroll
                for (int nt = 0; nt < 2; ++nt) {
                    const int kr = nt * 16 + fr;
                    half8 kf = *(const half8*)&Ktile[buf][(kr * 32 + ((c * 4 + g) ^ kkey)) * 8];
                    s[nt] = __builtin_amdgcn_mfma_f32_16x16x32_f16(qf[c], kf, s[nt], 0, 0, 0);
                }
            }
            __builtin_amdgcn_s_setprio(0);

            // ---- causal mask (log2 domain) ----
            const bool diag = (k0 + 31 > qw0);
            float sv[2][4];
            #pragma unroll
            for (int nt = 0; nt < 2; ++nt)
                #pragma unroll
                for (int reg = 0; reg < 4; ++reg) {
                    float v = s[nt][reg];
                    if (diag && (k0 + nt * 16 + fr > qw0 + g * 4 + reg)) v = -INFINITY;
                    sv[nt][reg] = v;
                }

            // ---- online softmax (rows on 16-lane groups) ----
            float alpha[4], psum[4];
            #pragma unroll
            for (int reg = 0; reg < 4; ++reg) {
                float tm = fmaxf(sv[0][reg], sv[1][reg]);
                tm = fmaxf(tm, __shfl_xor(tm, 1));
                tm = fmaxf(tm, __shfl_xor(tm, 2));
                tm = fmaxf(tm, __shfl_xor(tm, 4));
                tm = fmaxf(tm, __shfl_xor(tm, 8));
                const float mnew = fmaxf(mrow[reg], tm);
                alpha[reg] = exp2f(mrow[reg] - mnew);
                mrow[reg] = mnew;
                psum[reg] = 0.f;
            }
            #pragma unroll
            for (int nt = 0; nt < 2; ++nt)
                #pragma unroll
                for (int reg = 0; reg < 4; ++reg) {
                    const float pp = exp2f(sv[nt][reg] - mrow[reg]);
                    psum[reg] += pp;
                    Ps[w][(g * 4 + reg) * 72 + nt * 16 + fr] = f2h(pp);
                }
            #pragma unroll
            for (int reg = 0; reg < 4; ++reg) {
                float ps = psum[reg];
                ps += __shfl_xor(ps, 1);
                ps += __shfl_xor(ps, 2);
                ps += __shfl_xor(ps, 4);
                ps += __shfl_xor(ps, 8);
                lrow[reg] = lrow[reg] * alpha[reg] + ps;
            }
            #pragma unroll
            for (int dt = 0; dt < 16; ++dt)
                #pragma unroll
                for (int reg = 0; reg < 4; ++reg) o[dt][reg] *= alpha[reg];

            // ---- P as A-frag (k=0..31), wave-private LDS round-trip ----
            const half8 pf0 = *(const half8*)&Ps[w][fr * 72 + g * 8];

            // ---- PV: O[16q x 256d] += P * V ----
            const int vkey = g ^ ((fr >> 1) & 3);
            __builtin_amdgcn_s_setprio(1);
            #pragma unroll
            for (int dt = 0; dt < 16; ++dt) {
                const int dr = dt * 16 + fr;
                half8 vf = *(const half8*)&Vtile[buf][(dr * 4 + vkey) * 8];
                o[dt] = __builtin_amdgcn_mfma_f32_16x16x32_f16(pf0, vf, o[dt], 0, 0, 0);
            }
            __builtin_amdgcn_s_setprio(0);
        }
        __builtin_amdgcn_sched_barrier(0);
        __builtin_amdgcn_s_barrier();                // all waves done reading buf
        buf ^= 1;
    }

    // ---- epilogue: O /= l, write f16 into [B][T][H*D] ----
    float inv[4];
    #pragma unroll
    for (int reg = 0; reg < 4; ++reg) inv[reg] = 1.f / lrow[reg];
    const long rowbase = ((long)b * T_ + qw0 + g * 4) * E_ + h * D_;
    #pragma unroll
    for (int reg = 0; reg < 4; ++reg) {
        unsigned short* dst = Z2h + rowbase + (long)reg * E_ + fr;
        #pragma unroll
        for (int dt = 0; dt < 16; ++dt)
            dst[dt * 16] = f2h(o[dt][reg] * inv[reg]);
    }
}

// ---------------------------------------------------------------------------
// d_in: keys, values, queries, Wk, Wq, Wv, Wo, bo (fp32)
// ws (f16): Kp|Vp|Qp|Vt (4 x 12.6MB) | Z2h 12.6MB | WTk|WTq|WTv|WoT 4.7MB
// ---------------------------------------------------------------------------
extern "C" void kernel_launch(void* const* d_in, const int* in_sizes, int n_in,
                              void* d_out, int out_size, void* d_ws, size_t ws_size,
                              hipStream_t stream)
{
    const float* Xk = (const float*)d_in[0];
    const float* Xv = (const float*)d_in[1];
    const float* Xq = (const float*)d_in[2];
    const float* Wk = (const float*)d_in[3];
    const float* Wq = (const float*)d_in[4];
    const float* Wv = (const float*)d_in[5];
    const float* Wo = (const float*)d_in[6];
    const float* bo = (const float*)d_in[7];
    float* out = (float*)d_out;

    const size_t phd = (size_t)B_ * H_ * T_ * D_;   // 6,291,456
    const size_t wsz = (size_t)H_ * E_ * D_;        // 589,824
    unsigned short* Kp  = (unsigned short*)d_ws;
    unsigned short* Vp  = Kp + phd;
    unsigned short* Qp  = Vp + phd;
    unsigned short* Vt  = Qp + phd;
    unsigned short* Z2h = Vt + phd;
    unsigned short* WTk = Z2h + (size_t)B_ * T_ * E_;
    unsigned short* WTq = WTk + wsz;
    unsigned short* WTv = WTq + wsz;
    unsigned short* WoT = WTv + wsz;

    dim3 blk(256);

    // All weight transposes in one dispatch
    dim3 gtw(E_ / 32, E_ / 32, 10);                 // (24, 24, 10); x guarded for z<9
    transpose_cast_all<<<gtw, blk, 0, stream>>>(Wk, Wq, Wv, Wo, WTk, WTq, WTv, WoT);

    // Fused K/V/Q projections: one dispatch, 1152 blocks
    dim3 gproj(D_ / 128, T_ / 128, 36);
    qkv_proj<<<gproj, blk, 0, stream>>>(Xk, Xv, Xq, WTk, WTv, WTq, Kp, Vp, Qp);

    // V -> Vt [B*H][D][T]
    dim3 gtv(D_ / 64, T_ / 64, B_ * H_);
    transpose16<<<gtv, blk, 0, stream>>>(Vp, Vt, T_, D_);

    // Wave-paired LDS-staged MFMA flash attention -> Z2h f16 [B][T][H*D]
    dim3 gf(32 * B_ * H_);                          // 384 uniform blocks x 4 waves
    flash_lds<<<gf, blk, 0, stream>>>(Qp, Kp, Vt, Z2h,
                                      0.022097086912079608f * LOG2E);

    // Output projection: f16 Z * f16 Wo + bo -> fp32 out
    dim3 gout(E_ / 128, (B_ * T_) / 128, 1);
    gemm_mfma<false, false><<<gout, blk, 0, stream>>>(Z2h, WoT, out, bo, E_, 1, E_, E_,
                                                      0L, 0L, 0L);
}

// Round 11
// 202.164 us; speedup vs baseline: 11.6889x; 1.1457x over previous
//
#include <hip/hip_runtime.h>
#include <hip/hip_bf16.h>
#include <math.h>

#define B_ 4
#define T_ 2048
#define E_ 768
#define H_ 3
#define D_ 256
#define LOG2E 1.4426950408889634f

typedef __attribute__((ext_vector_type(8))) _Float16 half8;
typedef __attribute__((ext_vector_type(8))) unsigned short ushort8;
typedef __attribute__((ext_vector_type(4))) float f32x4;

static __device__ inline unsigned short f2h(float x) {
    _Float16 h = (_Float16)x;
    return *reinterpret_cast<unsigned short*>(&h);
}

#define GLOAD_LDS(SRC, DST) \
    __builtin_amdgcn_global_load_lds( \
        (const __attribute__((address_space(1))) void*)(SRC), \
        (__attribute__((address_space(3))) void*)(DST), 16, 0, 0)

// ---------------------------------------------------------------------------
// All weight transposes in ONE dispatch (validated R10).
// ---------------------------------------------------------------------------
__global__ __launch_bounds__(256)
void transpose_cast_all(const float* __restrict__ Wk, const float* __restrict__ Wq,
                        const float* __restrict__ Wv, const float* __restrict__ Wo,
                        unsigned short* __restrict__ WTk, unsigned short* __restrict__ WTq,
                        unsigned short* __restrict__ WTv, unsigned short* __restrict__ WoT)
{
    __shared__ float tile[32][33];
    const int z = blockIdx.z;
    const float* in; unsigned short* out; int R, C;
    if (z < 9) {
        const int mat = z / 3, hd = z % 3;
        R = E_; C = D_;
        in  = (mat == 0 ? Wk  : mat == 1 ? Wq  : Wv)  + (long)hd * E_ * D_;
        out = (mat == 0 ? WTk : mat == 1 ? WTq : WTv) + (long)hd * D_ * E_;
    } else {
        R = E_; C = E_;
        in = Wo; out = WoT;
    }
    const int c0 = blockIdx.x * 32;
    const int r0 = blockIdx.y * 32;
    if (c0 >= C) return;
    const int t  = threadIdx.x;
    const int cc = t & 31, rr = t >> 5;
    #pragma unroll
    for (int i = 0; i < 4; ++i)
        tile[rr + i * 8][cc] = in[(long)(r0 + rr + i * 8) * C + c0 + cc];
    __syncthreads();
    const int rr2 = t & 31, cc2 = t >> 5;
    #pragma unroll
    for (int i = 0; i < 4; ++i)
        out[(long)(c0 + cc2 + i * 8) * R + r0 + rr2] = f2h(tile[rr2][cc2 + i * 8]);
}

// ---------------------------------------------------------------------------
// fp16 transpose (validated R6-R10).
// ---------------------------------------------------------------------------
__global__ __launch_bounds__(256)
void transpose16(const unsigned short* __restrict__ in, unsigned short* __restrict__ out,
                 int R, int Ccols)
{
    __shared__ unsigned short tile[64 * 64];
    char* tb = (char*)tile;
    const long zoff = (long)blockIdx.z * R * Ccols;
    const int r0 = blockIdx.y * 64, c0 = blockIdx.x * 64;
    const int t = threadIdx.x;
    #pragma unroll
    for (int i = 0; i < 2; ++i) {
        const int rr = (t >> 3) + i * 32;
        const int gc = (t & 7) * 8;
        ushort8 v = *(const ushort8*)(in + zoff + (long)(r0 + rr) * Ccols + c0 + gc);
        *(ushort8*)(tb + rr * 128 + ((gc * 2) ^ (((rr >> 3) & 7) << 4))) = v;
    }
    __syncthreads();
    #pragma unroll
    for (int i = 0; i < 2; ++i) {
        const int cc = (t >> 3) + i * 32;
        const int gr = (t & 7) * 8;
        ushort8 v;
        #pragma unroll
        for (int e = 0; e < 8; ++e) {
            const int row = gr + e;
            v[e] = *(const unsigned short*)(tb + row * 128 + ((cc * 2) ^ (((row >> 3) & 7) << 4)));
        }
        *(ushort8*)(out + zoff + (long)(c0 + cc) * R + r0 + gr) = v;
    }
}

// ---------------------------------------------------------------------------
// fp16 MFMA GEMM body (validated R6-R10).
// ---------------------------------------------------------------------------
template<bool CONVA, bool OUT16>
__device__ __forceinline__
void gemm_body(const float* Af, const unsigned short* Ah, const unsigned short* Bz,
               void* Cz, const float* bias, int K, int lda, int ldc,
               int m0, int n0, int tid)
{
    __shared__ unsigned short As[128 * 32];
    __shared__ unsigned short Bs[128 * 32];

    const int lane = tid & 63, wid = tid >> 6;
    const int wm = wid >> 1, wn = wid & 1;
    const int fr = lane & 15, fg = lane >> 4;

    f32x4 acc[4][4];
    #pragma unroll
    for (int mt = 0; mt < 4; ++mt)
        #pragma unroll
        for (int nt = 0; nt < 4; ++nt) acc[mt][nt] = (f32x4)(0.f);

    for (int k0 = 0; k0 < K; k0 += 32) {
        #pragma unroll
        for (int i = 0; i < 2; ++i) {
            const int G = tid + i * 256;
            const int row = G >> 2, g = G & 3;
            ushort8 pa;
            if (CONVA) {
                const float* s = Af + (long)(m0 + row) * lda + k0 + g * 8;
                float4 f0 = *(const float4*)s, f1 = *(const float4*)(s + 4);
                pa[0] = f2h(f0.x); pa[1] = f2h(f0.y); pa[2] = f2h(f0.z); pa[3] = f2h(f0.w);
                pa[4] = f2h(f1.x); pa[5] = f2h(f1.y); pa[6] = f2h(f1.z); pa[7] = f2h(f1.w);
            } else {
                pa = *(const ushort8*)(Ah + (long)(m0 + row) * lda + k0 + g * 8);
            }
            *(ushort8*)&As[row * 32 + g * 8] = pa;
            *(ushort8*)&Bs[row * 32 + g * 8] =
                *(const ushort8*)(Bz + (long)(n0 + row) * K + k0 + g * 8);
        }
        __syncthreads();

        half8 a[4], b[4];
        #pragma unroll
        for (int mt = 0; mt < 4; ++mt)
            a[mt] = *(const half8*)&As[(wm * 64 + mt * 16 + fr) * 32 + fg * 8];
        #pragma unroll
        for (int nt = 0; nt < 4; ++nt)
            b[nt] = *(const half8*)&Bs[(wn * 64 + nt * 16 + fr) * 32 + fg * 8];
        #pragma unroll
        for (int mt = 0; mt < 4; ++mt)
            #pragma unroll
            for (int nt = 0; nt < 4; ++nt)
                acc[mt][nt] = __builtin_amdgcn_mfma_f32_16x16x32_f16(
                                  a[mt], b[nt], acc[mt][nt], 0, 0, 0);
        __syncthreads();
    }

    #pragma unroll
    for (int nt = 0; nt < 4; ++nt) {
        const int col = n0 + wn * 64 + nt * 16 + fr;
        const float badd = bias ? bias[col] : 0.f;
        #pragma unroll
        for (int mt = 0; mt < 4; ++mt) {
            const int row = m0 + wm * 64 + mt * 16 + fg * 4;
            #pragma unroll
            for (int reg = 0; reg < 4; ++reg) {
                if (OUT16)
                    ((unsigned short*)Cz)[(long)(row + reg) * ldc + col] =
                        f2h(acc[mt][nt][reg] + badd);
                else
                    ((float*)Cz)[(long)(row + reg) * ldc + col] =
                        acc[mt][nt][reg] + badd;
            }
        }
    }
}

template<bool CONVA, bool OUT16>
__global__ __launch_bounds__(256)
void gemm_mfma(const void* __restrict__ Av, const unsigned short* __restrict__ Bt,
               void* __restrict__ Cv, const float* __restrict__ bias,
               int K, int Hdiv, int lda, int ldc, long sA, long sB, long sC)
{
    const int z = blockIdx.z;
    const float*          Af = (const float*)Av          + (long)(z / Hdiv) * sA;
    const unsigned short* Ah = (const unsigned short*)Av + (long)(z / Hdiv) * sA;
    const unsigned short* Bz = Bt + (long)(z % Hdiv) * sB;
    void* Cz = OUT16 ? (void*)((unsigned short*)Cv + (long)z * sC)
                     : (void*)((float*)Cv + (long)z * sC);
    gemm_body<CONVA, OUT16>(Af, Ah, Bz, Cz, bias, K, lda, ldc,
                            blockIdx.y * 128, blockIdx.x * 128, threadIdx.x);
}

__global__ __launch_bounds__(256)
void qkv_proj(const float* __restrict__ Xk, const float* __restrict__ Xv,
              const float* __restrict__ Xq,
              const unsigned short* __restrict__ WTk, const unsigned short* __restrict__ WTv,
              const unsigned short* __restrict__ WTq,
              unsigned short* __restrict__ Kp, unsigned short* __restrict__ Vp,
              unsigned short* __restrict__ Qp)
{
    const int z = blockIdx.z;
    const int which = z / 12, bh = z % 12;
    const int b = bh / H_, h = bh % H_;
    const float* X = (which == 0) ? Xk : (which == 1) ? Xv : Xq;
    const unsigned short* W = (which == 0) ? WTk : (which == 1) ? WTv : WTq;
    unsigned short* P = (which == 0) ? Kp : (which == 1) ? Vp : Qp;
    const float* Af = X + (long)b * T_ * E_;
    const unsigned short* Bz = W + (long)h * D_ * E_;
    unsigned short* Cz = P + (long)bh * T_ * D_;
    gemm_body<true, true>(Af, nullptr, Bz, Cz, nullptr, E_, E_, D_,
                          blockIdx.y * 128, blockIdx.x * 128, threadIdx.x);
}

// ---------------------------------------------------------------------------
// Wave-paired LDS-staged MFMA flash attention (R10 structure) + DEFER-MAX
// softmax (T13, THR=8) + per-lane deferred l-reduction.
// Common path per iteration: 7 fmax + 1 ballot + 8 exp2 + Ps write — no
// cross-lane reduces, no alpha, no o-rescale. Rare path (first tile / max
// jump > 8): full shfl-reduce + rescale of o and lrow.
// NaN-safety: any lane holding a finite sv while its mrow=-inf fails the
// __all -> full path runs; every wave's first tile has k=0 live in lane fr=0.
// ---------------------------------------------------------------------------
__global__ __launch_bounds__(256, 2)
void flash_lds(const unsigned short* __restrict__ Qb, const unsigned short* __restrict__ Kb,
               const unsigned short* __restrict__ Vtb, unsigned short* __restrict__ Z2h,
               float scale_log2e)
{
    __shared__ unsigned short Ktile[2][32 * 256];   // 16KB each
    __shared__ unsigned short Vtile[2][256 * 32];   // 16KB each
    __shared__ unsigned short Ps[4][16 * 72];       // 9KB

    const int p  = blockIdx.x;
    const int bh = p % 12;
    const int pi = p / 12;                     // 0..31
    const int qtB = 63 - pi;
    const int b = bh / H_, h = bh % H_;
    const int tid = threadIdx.x;
    const int w = tid >> 6, lane = tid & 63;
    const int g = lane >> 4, fr = lane & 15;
    const int qw0 = (w < 2) ? (pi * 32 + w * 16) : (qtB * 32 + (w - 2) * 16);

    const unsigned short* kg = Kb  + (long)bh * T_ * D_;
    const unsigned short* vg = Vtb + (long)bh * D_ * T_;

    const unsigned short* qrow = Qb + ((long)bh * T_ + qw0 + fr) * D_;
    const _Float16 hs = (_Float16)scale_log2e;
    half8 qf[8];
    #pragma unroll
    for (int c = 0; c < 8; ++c) {
        qf[c] = *(const half8*)(qrow + c * 32 + g * 8);
        qf[c] *= hs;
    }

    f32x4 o[16];
    #pragma unroll
    for (int dt = 0; dt < 16; ++dt) o[dt] = (f32x4)(0.f);
    float mrow[4] = {-INFINITY, -INFINITY, -INFINITY, -INFINITY};
    float lrow[4] = {0.f, 0.f, 0.f, 0.f};     // PER-LANE partials (deferred reduce)

    const int nkt = qtB + 1;

    auto STAGE = [&](int bufi, int kt) {
        const int k0 = kt * 32;
        #pragma unroll
        for (int i = 0; i < 4; ++i) {
            const int L = tid + i * 256;
            const int r = L >> 5, cg = L & 31;
            GLOAD_LDS(kg + (long)(k0 + r) * D_ + ((cg ^ (r & 7)) * 8),
                      &Ktile[bufi][L * 8]);
        }
        #pragma unroll
        for (int i = 0; i < 4; ++i) {
            const int L = tid + i * 256;
            const int dr = L >> 2, gq = L & 3;
            GLOAD_LDS(vg + (long)dr * T_ + k0 + ((gq ^ ((dr >> 1) & 3)) * 8),
                      &Vtile[bufi][L * 8]);
        }
    };

    STAGE(0, 0);
    int buf = 0;
    for (int kt = 0; kt < nkt; ++kt) {
        const bool pf = (kt + 1 < nkt);
        if (pf) {
            STAGE(buf ^ 1, kt + 1);
            asm volatile("s_waitcnt vmcnt(8)" ::: "memory");
        } else {
            asm volatile("s_waitcnt vmcnt(0)" ::: "memory");
        }
        __builtin_amdgcn_sched_barrier(0);
        __builtin_amdgcn_s_barrier();
        __builtin_amdgcn_sched_barrier(0);

        const int k0 = kt * 32;
        if (k0 <= qw0 + 15) {
            // ---- QK^T: S[16q x 32k] ----
            f32x4 s[2];
            s[0] = (f32x4)(0.f); s[1] = (f32x4)(0.f);
            const int kkey = fr & 7;
            __builtin_amdgcn_s_setprio(1);
            #pragma unroll
            for (int c = 0; c < 8; ++c) {
                #pragma unroll
                for (int nt = 0; nt < 2; ++nt) {
                    const int kr = nt * 16 + fr;
                    half8 kf = *(const half8*)&Ktile[buf][(kr * 32 + ((c * 4 + g) ^ kkey)) * 8];
                    s[nt] = __builtin_amdgcn_mfma_f32_16x16x32_f16(qf[c], kf, s[nt], 0, 0, 0);
                }
            }
            __builtin_amdgcn_s_setprio(0);

            // ---- causal mask (log2 domain) ----
            const bool diag = (k0 + 31 > qw0);
            float sv[2][4];
            #pragma unroll
            for (int nt = 0; nt < 2; ++nt)
                #pragma unroll
                for (int reg = 0; reg < 4; ++reg) {
                    float v = s[nt][reg];
                    if (diag && (k0 + nt * 16 + fr > qw0 + g * 4 + reg)) v = -INFINITY;
                    sv[nt][reg] = v;
                }

            // ---- defer-max online softmax ----
            float pmax[4];
            #pragma unroll
            for (int reg = 0; reg < 4; ++reg) pmax[reg] = fmaxf(sv[0][reg], sv[1][reg]);
            const bool ok = (pmax[0] <= mrow[0] + 8.f) && (pmax[1] <= mrow[1] + 8.f)
                         && (pmax[2] <= mrow[2] + 8.f) && (pmax[3] <= mrow[3] + 8.f);
            if (!__all(ok)) {
                // rare path: full per-row reduce + rescale
                #pragma unroll
                for (int reg = 0; reg < 4; ++reg) {
                    float tm = pmax[reg];
                    tm = fmaxf(tm, __shfl_xor(tm, 1));
                    tm = fmaxf(tm, __shfl_xor(tm, 2));
                    tm = fmaxf(tm, __shfl_xor(tm, 4));
                    tm = fmaxf(tm, __shfl_xor(tm, 8));
                    const float mnew = fmaxf(mrow[reg], tm);
                    const float alpha = exp2f(mrow[reg] - mnew);
                    mrow[reg] = mnew;
                    lrow[reg] *= alpha;
                    #pragma unroll
                    for (int dt = 0; dt < 16; ++dt) o[dt][reg] *= alpha;
                }
            }
            #pragma unroll
            for (int nt = 0; nt < 2; ++nt)
                #pragma unroll
                for (int reg = 0; reg < 4; ++reg) {
                    const float pp = exp2f(sv[nt][reg] - mrow[reg]);
                    lrow[reg] += pp;                       // per-lane partial
                    Ps[w][(g * 4 + reg) * 72 + nt * 16 + fr] = f2h(pp);
                }

            // ---- P as A-frag ----
            const half8 pf0 = *(const half8*)&Ps[w][fr * 72 + g * 8];

            // ---- PV: O[16q x 256d] += P * V ----
            const int vkey = g ^ ((fr >> 1) & 3);
            __builtin_amdgcn_s_setprio(1);
            #pragma unroll
            for (int dt = 0; dt < 16; ++dt) {
                const int dr = dt * 16 + fr;
                half8 vf = *(const half8*)&Vtile[buf][(dr * 4 + vkey) * 8];
                o[dt] = __builtin_amdgcn_mfma_f32_16x16x32_f16(pf0, vf, o[dt], 0, 0, 0);
            }
            __builtin_amdgcn_s_setprio(0);
        }
        __builtin_amdgcn_sched_barrier(0);
        __builtin_amdgcn_s_barrier();
        buf ^= 1;
    }

    // ---- epilogue: reduce lrow across fr lanes, O /= l, write f16 ----
    float inv[4];
    #pragma unroll
    for (int reg = 0; reg < 4; ++reg) {
        float ps = lrow[reg];
        ps += __shfl_xor(ps, 1);
        ps += __shfl_xor(ps, 2);
        ps += __shfl_xor(ps, 4);
        ps += __shfl_xor(ps, 8);
        inv[reg] = 1.f / ps;
    }
    const long rowbase = ((long)b * T_ + qw0 + g * 4) * E_ + h * D_;
    #pragma unroll
    for (int reg = 0; reg < 4; ++reg) {
        unsigned short* dst = Z2h + rowbase + (long)reg * E_ + fr;
        #pragma unroll
        for (int dt = 0; dt < 16; ++dt)
            dst[dt * 16] = f2h(o[dt][reg] * inv[reg]);
    }
}

// ---------------------------------------------------------------------------
// d_in: keys, values, queries, Wk, Wq, Wv, Wo, bo (fp32)
// ws (f16): Kp|Vp|Qp|Vt (4 x 12.6MB) | Z2h 12.6MB | WTk|WTq|WTv|WoT 4.7MB
// ---------------------------------------------------------------------------
extern "C" void kernel_launch(void* const* d_in, const int* in_sizes, int n_in,
                              void* d_out, int out_size, void* d_ws, size_t ws_size,
                              hipStream_t stream)
{
    const float* Xk = (const float*)d_in[0];
    const float* Xv = (const float*)d_in[1];
    const float* Xq = (const float*)d_in[2];
    const float* Wk = (const float*)d_in[3];
    const float* Wq = (const float*)d_in[4];
    const float* Wv = (const float*)d_in[5];
    const float* Wo = (const float*)d_in[6];
    const float* bo = (const float*)d_in[7];
    float* out = (float*)d_out;

    const size_t phd = (size_t)B_ * H_ * T_ * D_;   // 6,291,456
    const size_t wsz = (size_t)H_ * E_ * D_;        // 589,824
    unsigned short* Kp  = (unsigned short*)d_ws;
    unsigned short* Vp  = Kp + phd;
    unsigned short* Qp  = Vp + phd;
    unsigned short* Vt  = Qp + phd;
    unsigned short* Z2h = Vt + phd;
    unsigned short* WTk = Z2h + (size_t)B_ * T_ * E_;
    unsigned short* WTq = WTk + wsz;
    unsigned short* WTv = WTq + wsz;
    unsigned short* WoT = WTv + wsz;

    dim3 blk(256);

    dim3 gtw(E_ / 32, E_ / 32, 10);
    transpose_cast_all<<<gtw, blk, 0, stream>>>(Wk, Wq, Wv, Wo, WTk, WTq, WTv, WoT);

    dim3 gproj(D_ / 128, T_ / 128, 36);
    qkv_proj<<<gproj, blk, 0, stream>>>(Xk, Xv, Xq, WTk, WTv, WTq, Kp, Vp, Qp);

    dim3 gtv(D_ / 64, T_ / 64, B_ * H_);
    transpose16<<<gtv, blk, 0, stream>>>(Vp, Vt, T_, D_);

    dim3 gf(32 * B_ * H_);                          // 384 uniform blocks x 4 waves
    flash_lds<<<gf, blk, 0, stream>>>(Qp, Kp, Vt, Z2h,
                                      0.022097086912079608f * LOG2E);

    dim3 gout(E_ / 128, (B_ * T_) / 128, 1);
    gemm_mfma<false, false><<<gout, blk, 0, stream>>>(Z2h, WoT, out, bo, E_, 1, E_, E_,
                                                      0L, 0L, 0L);
}